// Round 1
// baseline (1795.134 us; speedup 1.0000x reference)
//
#include <hip/hip_runtime.h>

// ---------------- constants ----------------
#define BB   32
#define SS   1024
#define DD   1024
#define SMM  1023
#define NER  17
#define HH   512
#define DXX  1041
#define PP   10
#define NPAIR 90

// ---------------- K1: C1 = relu(h @ W1 + b1), M=32768 N=1024 K=1024, fp32 ----------------
__global__ __launch_bounds__(256) void k_gemm1(const float* __restrict__ A,
                                               const float* __restrict__ Bm,
                                               const float* __restrict__ bias,
                                               float* __restrict__ C) {
  __shared__ float As[16][128];
  __shared__ float Bs[16][128];
  const int tid = threadIdx.x;
  const int tx = tid & 15, ty = tid >> 4;
  const int n0 = blockIdx.x * 128, m0 = blockIdx.y * 128;
  const int ar = tid >> 1, ak = (tid & 1) * 8;
  const int bk = tid >> 4, bc = (tid & 15) * 8;
  float acc[2][2][4][4] = {};
  for (int k0 = 0; k0 < 1024; k0 += 16) {
    float4 a0 = *(const float4*)(A + (size_t)(m0 + ar) * 1024 + k0 + ak);
    float4 a1 = *(const float4*)(A + (size_t)(m0 + ar) * 1024 + k0 + ak + 4);
    float4 b0 = *(const float4*)(Bm + (size_t)(k0 + bk) * 1024 + n0 + bc);
    float4 b1v = *(const float4*)(Bm + (size_t)(k0 + bk) * 1024 + n0 + bc + 4);
    __syncthreads();
    As[ak + 0][ar] = a0.x; As[ak + 1][ar] = a0.y; As[ak + 2][ar] = a0.z; As[ak + 3][ar] = a0.w;
    As[ak + 4][ar] = a1.x; As[ak + 5][ar] = a1.y; As[ak + 6][ar] = a1.z; As[ak + 7][ar] = a1.w;
    *(float4*)&Bs[bk][bc] = b0;
    *(float4*)&Bs[bk][bc + 4] = b1v;
    __syncthreads();
#pragma unroll
    for (int kk = 0; kk < 16; ++kk) {
      float4 aA = *(const float4*)&As[kk][ty * 4];
      float4 aB = *(const float4*)&As[kk][64 + ty * 4];
      float4 bA = *(const float4*)&Bs[kk][tx * 4];
      float4 bB = *(const float4*)&Bs[kk][64 + tx * 4];
      float av[2][4] = {{aA.x, aA.y, aA.z, aA.w}, {aB.x, aB.y, aB.z, aB.w}};
      float bv[2][4] = {{bA.x, bA.y, bA.z, bA.w}, {bB.x, bB.y, bB.z, bB.w}};
#pragma unroll
      for (int ri = 0; ri < 2; ++ri)
#pragma unroll
        for (int i = 0; i < 4; ++i)
#pragma unroll
          for (int rj = 0; rj < 2; ++rj)
#pragma unroll
            for (int j = 0; j < 4; ++j)
              acc[ri][rj][i][j] = fmaf(av[ri][i], bv[rj][j], acc[ri][rj][i][j]);
    }
  }
#pragma unroll
  for (int ri = 0; ri < 2; ++ri)
#pragma unroll
    for (int i = 0; i < 4; ++i) {
      int row = m0 + ri * 64 + ty * 4 + i;
#pragma unroll
      for (int rj = 0; rj < 2; ++rj) {
        int col = n0 + rj * 64 + tx * 4;
        float4 o;
        o.x = fmaxf(acc[ri][rj][i][0] + bias[col + 0], 0.f);
        o.y = fmaxf(acc[ri][rj][i][1] + bias[col + 1], 0.f);
        o.z = fmaxf(acc[ri][rj][i][2] + bias[col + 2], 0.f);
        o.w = fmaxf(acc[ri][rj][i][3] + bias[col + 3], 0.f);
        *(float4*)(C + (size_t)row * 1024 + col) = o;
      }
    }
}

// ---------------- K2: ner = C1 @ W2 + b2; softmax; argmax; emit ner_o ----------------
__global__ __launch_bounds__(256) void k_ner(const float* __restrict__ C1,
                                             const float* __restrict__ W2,
                                             const float* __restrict__ b2,
                                             float* __restrict__ ner_out,
                                             float* __restrict__ softm,
                                             int* __restrict__ amax) {
  const int wave = threadIdx.x >> 6, lane = threadIdx.x & 63;
  const int row0 = blockIdx.x * 16 + wave * 4;
  float acc[4][17];
#pragma unroll
  for (int r = 0; r < 4; ++r)
#pragma unroll
    for (int c = 0; c < 17; ++c) acc[r][c] = 0.f;
  for (int kb = 0; kb < 16; ++kb) {
    int k = kb * 64 + lane;
    float w2l[17];
#pragma unroll
    for (int c = 0; c < 17; ++c) w2l[c] = W2[k * 17 + c];
#pragma unroll
    for (int r = 0; r < 4; ++r) {
      float v = C1[(size_t)(row0 + r) * 1024 + k];
#pragma unroll
      for (int c = 0; c < 17; ++c) acc[r][c] = fmaf(v, w2l[c], acc[r][c]);
    }
  }
#pragma unroll
  for (int off = 32; off > 0; off >>= 1) {
#pragma unroll
    for (int r = 0; r < 4; ++r)
#pragma unroll
      for (int c = 0; c < 17; ++c) acc[r][c] += __shfl_xor(acc[r][c], off);
  }
  if (lane < 4) {
    const int row = row0 + lane;
    float v[17];
#pragma unroll
    for (int c = 0; c < 17; ++c) v[c] = acc[lane][c] + b2[c];
    float mx = v[0]; int am = 0;
#pragma unroll
    for (int c = 1; c < 17; ++c) { if (v[c] > mx) { mx = v[c]; am = c; } }
    float s = 0.f, e[17];
#pragma unroll
    for (int c = 0; c < 17; ++c) { e[c] = __expf(v[c] - mx); s += e[c]; }
    const float inv = 1.f / s;
    float* sm = softm + (size_t)row * 17;
#pragma unroll
    for (int c = 0; c < 17; ++c) sm[c] = e[c] * inv;
    amax[row] = am;
    const int b = row >> 10, sidx = row & 1023;
    if (sidx >= 1) {
      float* no = ner_out + ((size_t)b * SMM + sidx - 1) * 17;
#pragma unroll
      for (int c = 0; c < 17; ++c) no[c] = v[c];
    }
  }
}

// ---------------- K3: span logic + entity selection + pos_pairs output ----------------
__global__ __launch_bounds__(64) void k_spans(const int* __restrict__ amax,
                                              int* __restrict__ meta,
                                              float* __restrict__ pp_out) {
  const int b = blockIdx.x, lane = threadIdx.x;
  __shared__ int nextE[4][1023];
  __shared__ int slist[4][10], blj[4][10], ble[4][10];
  __shared__ int ns[4], nb[4];
  __shared__ int posq[10];
  const int* am = amax + b * 1024 + 1;  // shifted: am[j] = argmax of token j+1
  if (lane < 4) {
    const int t = lane;
    int cur = SMM;
    for (int j = SMM - 1; j >= 0; --j) {
      nextE[t][j] = cur;
      if (am[j] == 3 + 4 * t) cur = j;
    }
    int end = -1, cs = 0, cb = 0;
    for (int j = 0; j < SMM; ++j) {
      int a = am[j];
      if (a == 4 + 4 * t && cs < 10) slist[t][cs++] = j;
      if (a == 1 + 4 * t && j > end) {
        end = nextE[t][j];
        if (cb < 10) { blj[t][cb] = j; ble[t][cb] = end; cb++; }
      }
    }
    ns[t] = cs; nb[t] = cb;
  }
  __syncthreads();
  if (lane == 0) {
    int q = 0;
    for (int t = 0; t < 4 && q < 10; ++t) {
      for (int s = 0; s < ns[t] && q < 10; ++s) {
        int j = slist[t][s];
        int* m = meta + (b * 10 + q) * 4;
        m[0] = j; m[1] = j + 1; m[2] = 1; m[3] = 1;
        posq[q] = j + 1; ++q;
      }
      for (int s = 0; s < nb[t] && q < 10; ++s) {
        int j = blj[t][s], e = ble[t][s];
        int* m = meta + (b * 10 + q) * 4;
        m[0] = j; m[1] = e; m[2] = e - j; m[3] = 1;
        posq[q] = e + 1; ++q;
      }
    }
    for (; q < 10; ++q) {
      int* m = meta + (b * 10 + q) * 4;
      m[0] = 0; m[1] = 0; m[2] = 1; m[3] = 0;
      posq[q] = -1;
    }
  }
  __syncthreads();
  for (int pr = lane; pr < NPAIR; pr += 64) {
    int i = pr / 9, jj = pr % 9;
    int j = jj + (jj >= i ? 1 : 0);
    pp_out[(size_t)(b * NPAIR + pr) * 2 + 0] = (float)posq[i];
    pp_out[(size_t)(b * NPAIR + pr) * 2 + 1] = (float)posq[j];
  }
}

// ---------------- K4: ents = segment means over x = [h | softm] (shifted) ----------------
__global__ __launch_bounds__(256) void k_ents(const float* __restrict__ h,
                                              const float* __restrict__ softm,
                                              const int* __restrict__ meta,
                                              float* __restrict__ ents) {
  const int bq = blockIdx.x;
  const int b = bq / 10;
  const int* m = meta + bq * 4;
  const int j0 = m[0], e = m[1], len = m[2], vs = m[3];
  float acc[5] = {0.f, 0.f, 0.f, 0.f, 0.f};
  for (int row = j0; row < e; ++row) {
    const int s = row + 1;
    const float* hr = h + (size_t)(b * 1024 + s) * 1024;
    const float* sr = softm + (size_t)(b * 1024 + s) * 17;
#pragma unroll
    for (int i = 0; i < 5; ++i) {
      int d = threadIdx.x + i * 256;
      if (d < DXX) acc[i] += (d < 1024 ? hr[d] : sr[d - 1024]);
    }
  }
  const float inv = vs ? (1.0f / (float)len) : 0.0f;
#pragma unroll
  for (int i = 0; i < 5; ++i) {
    int d = threadIdx.x + i * 256;
    if (d < DXX) ents[(size_t)bq * DXX + d] = acc[i] * inv;
  }
}

// ---------------- K5: generic small GEMM  C = [relu](A@B + bias), tiled ----------------
__global__ __launch_bounds__(256) void k_mlp(const float* __restrict__ A,
                                             const float* __restrict__ Bm,
                                             const float* __restrict__ bias,
                                             float* __restrict__ C,
                                             int M, int N, int K, int dorelu,
                                             long long bzs, long long czs) {
  const float* Bz = Bm + (size_t)blockIdx.z * bzs;
  float* Cz = C + (size_t)blockIdx.z * czs;
  __shared__ float As[16][64];
  const int n = blockIdx.x * 64 + (threadIdx.x & 63);
  const int rg = threadIdx.x >> 6;
  const int r0 = blockIdx.y * 16 + rg * 4;
  float acc[4] = {0.f, 0.f, 0.f, 0.f};
  for (int k0 = 0; k0 < K; k0 += 64) {
    __syncthreads();
    for (int idx = threadIdx.x; idx < 16 * 64; idx += 256) {
      int r = idx >> 6, kk = idx & 63;
      int k = k0 + kk;
      int row = blockIdx.y * 16 + r;
      As[r][kk] = (k < K && row < M) ? A[(size_t)row * K + k] : 0.f;
    }
    __syncthreads();
    int kmax = (K - k0 < 64) ? (K - k0) : 64;
    for (int kk = 0; kk < kmax; ++kk) {
      float bv = Bz[(size_t)(k0 + kk) * N + n];
#pragma unroll
      for (int i = 0; i < 4; ++i) acc[i] = fmaf(As[rg * 4 + i][kk], bv, acc[i]);
    }
  }
  float bb = bias ? bias[n] : 0.f;
#pragma unroll
  for (int i = 0; i < 4; ++i) {
    int row = r0 + i;
    if (row < M) {
      float v = acc[i] + bb;
      if (dorelu) v = fmaxf(v, 0.f);
      Cz[(size_t)row * N + n] = v;
    }
  }
}

// ---------------- K6: lh/lt = head/tail @ Wlin parts ----------------
__global__ __launch_bounds__(64) void k_lin(const float* __restrict__ headp,
                                            const float* __restrict__ tailp,
                                            const float* __restrict__ Wlin,
                                            float* __restrict__ lh,
                                            float* __restrict__ lt) {
  const int r = blockIdx.x, l = threadIdx.x;
  float a[16], bacc[16];
#pragma unroll
  for (int o = 0; o < 16; ++o) { a[o] = 0.f; bacc[o] = 0.f; }
  for (int k = l; k < 512; k += 64) {
    float hv = headp[(size_t)r * 512 + k];
    float tv = tailp[(size_t)r * 512 + k];
#pragma unroll
    for (int o = 0; o < 16; ++o) {
      a[o] = fmaf(hv, Wlin[o * 1024 + k], a[o]);
      bacc[o] = fmaf(tv, Wlin[o * 1024 + 512 + k], bacc[o]);
    }
  }
#pragma unroll
  for (int off = 32; off > 0; off >>= 1) {
#pragma unroll
    for (int o = 0; o < 16; ++o) {
      a[o] += __shfl_xor(a[o], off);
      bacc[o] += __shfl_xor(bacc[o], off);
    }
  }
  if (l == 0) {
#pragma unroll
    for (int o = 0; o < 16; ++o) {
      lh[r * 16 + o] = a[o];
      lt[r * 16 + o] = bacc[o];
    }
  }
}

// ---------------- K7: re = u[o,i]·tail[j] + bbil + lh + lt ----------------
__global__ __launch_bounds__(256) void k_re(const float* __restrict__ u,
                                            const float* __restrict__ tailp,
                                            const float* __restrict__ lh,
                                            const float* __restrict__ lt,
                                            const float* __restrict__ bbil,
                                            float* __restrict__ re_out) {
  const int bp = blockIdx.x;
  const int b = bp / NPAIR, pr = bp % NPAIR;
  const int i = pr / 9, jj = pr % 9;
  const int j = jj + (jj >= i ? 1 : 0);
  const int wave = threadIdx.x >> 6, lane = threadIdx.x & 63;
  const float* tj = tailp + (size_t)(b * 10 + j) * 512;
#pragma unroll
  for (int oo = 0; oo < 4; ++oo) {
    const int o = wave + oo * 4;
    const float* uo = u + ((size_t)o * 320 + b * 10 + i) * 512;
    float acc = 0.f;
    for (int k = lane; k < 512; k += 64) acc = fmaf(uo[k], tj[k], acc);
#pragma unroll
    for (int off = 32; off > 0; off >>= 1) acc += __shfl_xor(acc, off);
    if (lane == 0)
      re_out[(size_t)bp * 16 + o] = acc + bbil[o] + lh[(b * 10 + i) * 16 + o] + lt[(b * 10 + j) * 16 + o];
  }
}

// ---------------- launch ----------------
extern "C" void kernel_launch(void* const* d_in, const int* in_sizes, int n_in,
                              void* d_out, int out_size, void* d_ws, size_t ws_size,
                              hipStream_t stream) {
  const float* h    = (const float*)d_in[0];
  const float* W1   = (const float*)d_in[1];
  const float* b1   = (const float*)d_in[2];
  const float* W2   = (const float*)d_in[3];
  const float* b2   = (const float*)d_in[4];
  const float* Wh1  = (const float*)d_in[5];
  const float* bh1  = (const float*)d_in[6];
  const float* Wh2  = (const float*)d_in[7];
  const float* bh2  = (const float*)d_in[8];
  const float* Wt1  = (const float*)d_in[9];
  const float* bt1  = (const float*)d_in[10];
  const float* Wt2  = (const float*)d_in[11];
  const float* bt2  = (const float*)d_in[12];
  const float* Wbil = (const float*)d_in[13];
  const float* bbil = (const float*)d_in[14];
  const float* Wlin = (const float*)d_in[15];

  float* out = (float*)d_out;
  float* ner_out = out;                      // 32*1023*17 = 556512
  float* pp_out  = out + 556512;             // 32*90*2   = 5760
  float* re_out  = out + 562272;             // 32*90*16  = 46080

  char* ws = (char*)d_ws;
  float* C1    = (float*)(ws + 0);            // 134217728 B
  float* softm = (float*)(ws + 134217728);    // 2228224 B
  int*   amax  = (int*)  (ws + 136445952);    // 131072 B
  int*   meta  = (int*)  (ws + 136577024);    // 5120 B
  float* ents  = (float*)(ws + 136582144);    // 1332480 B
  float* H1    = (float*)(ws + 137914624);    // 655360 B
  float* T1    = (float*)(ws + 138569984);    // 655360 B
  float* headp = (float*)(ws + 139225344);    // 655360 B
  float* tailp = (float*)(ws + 139880704);    // 655360 B
  float* u     = (float*)(ws + 140536064);    // 10485760 B
  float* lh    = (float*)(ws + 151021824);    // 20480 B
  float* lt    = (float*)(ws + 151042304);    // 20480 B

  k_gemm1<<<dim3(8, 256), 256, 0, stream>>>(h, W1, b1, C1);
  k_ner<<<2048, 256, 0, stream>>>(C1, W2, b2, ner_out, softm, amax);
  k_spans<<<32, 64, 0, stream>>>(amax, meta, pp_out);
  k_ents<<<320, 256, 0, stream>>>(h, softm, meta, ents);
  k_mlp<<<dim3(8, 20, 1), 256, 0, stream>>>(ents, Wh1, bh1, H1, 320, 512, 1041, 1, 0, 0);
  k_mlp<<<dim3(8, 20, 1), 256, 0, stream>>>(H1, Wh2, bh2, headp, 320, 512, 512, 0, 0, 0);
  k_mlp<<<dim3(8, 20, 1), 256, 0, stream>>>(ents, Wt1, bt1, T1, 320, 512, 1041, 1, 0, 0);
  k_mlp<<<dim3(8, 20, 1), 256, 0, stream>>>(T1, Wt2, bt2, tailp, 320, 512, 512, 0, 0, 0);
  k_mlp<<<dim3(8, 20, 16), 256, 0, stream>>>(headp, Wbil, nullptr, u, 320, 512, 512, 0,
                                             (long long)512 * 512, (long long)320 * 512);
  k_lin<<<320, 64, 0, stream>>>(headp, tailp, Wlin, lh, lt);
  k_re<<<2880, 256, 0, stream>>>(u, tailp, lh, lt, bbil, re_out);
}

// Round 2
// 1611.803 us; speedup vs baseline: 1.1137x; 1.1137x over previous
//
#include <hip/hip_runtime.h>
#include <hip/hip_bf16.h>

// ---------------- constants ----------------
#define BB   32
#define SS   1024
#define DD   1024
#define SMM  1023
#define NER  17
#define HH   512
#define DXX  1041
#define PP   10
#define NPAIR 90

typedef __bf16 bf16x8 __attribute__((ext_vector_type(8)));
typedef float f32x4 __attribute__((ext_vector_type(4)));

// ---------------- split helpers ----------------
__device__ inline void split3(float x, unsigned short& s0, unsigned short& s1, unsigned short& s2) {
  __hip_bfloat16 h0 = __float2bfloat16(x);
  float f0 = __bfloat162float(h0);
  float r1 = x - f0;
  __hip_bfloat16 h1 = __float2bfloat16(r1);
  float f1 = __bfloat162float(h1);
  float r2 = r1 - f1;
  __hip_bfloat16 h2 = __float2bfloat16(r2);
  s0 = *reinterpret_cast<unsigned short*>(&h0);
  s1 = *reinterpret_cast<unsigned short*>(&h1);
  s2 = *reinterpret_cast<unsigned short*>(&h2);
}

// ---------------- K0a: split h into 3 bf16 planes ----------------
__global__ __launch_bounds__(256) void k_split_h(const float4* __restrict__ h4,
                                                 ushort4* __restrict__ p0,
                                                 ushort4* __restrict__ p1,
                                                 ushort4* __restrict__ p2) {
  const int idx = blockIdx.x * 256 + threadIdx.x;
  for (int i = idx; i < 8388608; i += 524288) {
    float4 v = h4[i];
    ushort4 a, b, c;
    split3(v.x, a.x, b.x, c.x);
    split3(v.y, a.y, b.y, c.y);
    split3(v.z, a.z, b.z, c.z);
    split3(v.w, a.w, b.w, c.w);
    p0[i] = a; p1[i] = b; p2[i] = c;
  }
}

// ---------------- K0b: split + transpose W1 -> 3 bf16 planes of W1^T [n][k] ----------------
__global__ __launch_bounds__(256) void k_split_w(const float* __restrict__ W,
                                                 unsigned short* __restrict__ wP) {
  __shared__ float t[32][33];
  const int bk = blockIdx.x * 32, bn = blockIdx.y * 32;
  const int tr = threadIdx.x >> 5, tc = threadIdx.x & 31;
#pragma unroll
  for (int i = 0; i < 4; ++i)
    t[tr + i * 8][tc] = W[(size_t)(bk + tr + i * 8) * 1024 + bn + tc];
  __syncthreads();
#pragma unroll
  for (int i = 0; i < 4; ++i) {
    const int n = bn + tr + i * 8, k = bk + tc;
    unsigned short s0, s1, s2;
    split3(t[tc][tr + i * 8], s0, s1, s2);
    wP[(size_t)n * 1024 + k] = s0;
    wP[1048576 + (size_t)n * 1024 + k] = s1;
    wP[2097152 + (size_t)n * 1024 + k] = s2;
  }
}

// ---------------- K0c: transpose W2 -> W2T[17][1024] ----------------
__global__ void k_w2t(const float* __restrict__ W2, float* __restrict__ W2T) {
  const int c = blockIdx.x, k = blockIdx.y * 256 + threadIdx.x;
  W2T[c * 1024 + k] = W2[k * 17 + c];
}

// ---------------- K1 (MFMA): C1 = relu(h@W1 + b1) via bf16x3 6-product, K'=6144 ----------------
__global__ __launch_bounds__(256) void k_gemm1_mfma(const unsigned short* __restrict__ hP,
                                                    const unsigned short* __restrict__ wP,
                                                    const float* __restrict__ bias,
                                                    float* __restrict__ C) {
  __shared__ unsigned short As[128 * 64];
  __shared__ unsigned short Bs[128 * 64];
  const int tid = threadIdx.x;
  const int w = tid >> 6, l = tid & 63;
  const int m0 = blockIdx.y * 128, n0 = blockIdx.x * 128;
  const int lo3 = l & 7;
  const int ksw = ((l & 7) ^ ((l >> 3) & 7)) * 8;  // pre-swizzled global k offset (elements)
  const int rbase = w * 8 + (l >> 3);              // + i*32 -> LDS row
  const int wm = w & 1, wn = w >> 1;
  const int trA = wm * 64 + (l & 15);
  const int trB = wn * 64 + (l & 15);
  const int slotbase = l >> 4;
  f32x4 acc[4][4];
#pragma unroll
  for (int i = 0; i < 4; ++i)
#pragma unroll
    for (int j = 0; j < 4; ++j) acc[i][j] = (f32x4){0.f, 0.f, 0.f, 0.f};

  // segment plane selectors: s=0..5 -> (a,b) = (2,0)(1,1)(0,2)(1,0)(0,1)(0,0), small terms first
  const unsigned saBits = 2u | (1u << 2) | (0u << 4) | (1u << 6) | (0u << 8) | (0u << 10);
  const unsigned sbBits = 0u | (1u << 2) | (2u << 4) | (0u << 6) | (1u << 8) | (0u << 10);

  for (int step = 0; step < 96; ++step) {
    const int s = step >> 4;
    const int k0 = (step & 15) << 6;
    const int pa = (saBits >> (2 * s)) & 3;
    const int pb = (sbBits >> (2 * s)) & 3;
    const unsigned short* Ab = hP + (size_t)pa * 33554432 + k0 + ksw;
    const unsigned short* Bb = wP + (size_t)pb * 1048576 + k0 + ksw;
#pragma unroll
    for (int i = 0; i < 4; ++i) {
      const int row = rbase + i * 32;
      __builtin_amdgcn_global_load_lds(
          (const __attribute__((address_space(1))) void*)(Ab + (size_t)(m0 + row) * 1024),
          (__attribute__((address_space(3))) void*)((char*)As + i * 4096 + w * 1024 + (l & 63) * 16),
          16, 0, 0);
    }
#pragma unroll
    for (int i = 0; i < 4; ++i) {
      const int row = rbase + i * 32;
      __builtin_amdgcn_global_load_lds(
          (const __attribute__((address_space(1))) void*)(Bb + (size_t)(n0 + row) * 1024),
          (__attribute__((address_space(3))) void*)((char*)Bs + i * 4096 + w * 1024 + (l & 63) * 16),
          16, 0, 0);
    }
    __syncthreads();
#pragma unroll
    for (int kk2 = 0; kk2 < 2; ++kk2) {
      bf16x8 af[4], bfr[4];
#pragma unroll
      for (int m = 0; m < 4; ++m) {
        const int row = trA + m * 16;
        const int byte = row * 128 + ((((kk2 << 2) + slotbase) ^ lo3) << 4);
        af[m] = *(const bf16x8*)((const char*)As + byte);
      }
#pragma unroll
      for (int n = 0; n < 4; ++n) {
        const int row = trB + n * 16;
        const int byte = row * 128 + ((((kk2 << 2) + slotbase) ^ lo3) << 4);
        bfr[n] = *(const bf16x8*)((const char*)Bs + byte);
      }
#pragma unroll
      for (int m = 0; m < 4; ++m)
#pragma unroll
        for (int n = 0; n < 4; ++n)
          acc[m][n] = __builtin_amdgcn_mfma_f32_16x16x32_bf16(af[m], bfr[n], acc[m][n], 0, 0, 0);
    }
    __syncthreads();
  }
  const int crow0 = m0 + wm * 64 + (l >> 4) * 4;
  const int ccol0 = n0 + wn * 64 + (l & 15);
#pragma unroll
  for (int n = 0; n < 4; ++n) {
    const int col = ccol0 + n * 16;
    const float bb = bias[col];
#pragma unroll
    for (int m = 0; m < 4; ++m)
#pragma unroll
      for (int r = 0; r < 4; ++r) {
        const int row = crow0 + m * 16 + r;
        C[(size_t)row * 1024 + col] = fmaxf(acc[m][n][r] + bb, 0.f);
      }
  }
}

// ---------------- K1-fallback: fp32 vector GEMM (used when ws too small) ----------------
__global__ __launch_bounds__(256) void k_gemm1(const float* __restrict__ A,
                                               const float* __restrict__ Bm,
                                               const float* __restrict__ bias,
                                               float* __restrict__ C) {
  __shared__ float As[16][128];
  __shared__ float Bsh[16][128];
  const int tid = threadIdx.x;
  const int tx = tid & 15, ty = tid >> 4;
  const int n0 = blockIdx.x * 128, m0 = blockIdx.y * 128;
  const int ar = tid >> 1, ak = (tid & 1) * 8;
  const int bk = tid >> 4, bc = (tid & 15) * 8;
  float acc[2][2][4][4] = {};
  for (int k0 = 0; k0 < 1024; k0 += 16) {
    float4 a0 = *(const float4*)(A + (size_t)(m0 + ar) * 1024 + k0 + ak);
    float4 a1 = *(const float4*)(A + (size_t)(m0 + ar) * 1024 + k0 + ak + 4);
    float4 b0 = *(const float4*)(Bm + (size_t)(k0 + bk) * 1024 + n0 + bc);
    float4 b1v = *(const float4*)(Bm + (size_t)(k0 + bk) * 1024 + n0 + bc + 4);
    __syncthreads();
    As[ak + 0][ar] = a0.x; As[ak + 1][ar] = a0.y; As[ak + 2][ar] = a0.z; As[ak + 3][ar] = a0.w;
    As[ak + 4][ar] = a1.x; As[ak + 5][ar] = a1.y; As[ak + 6][ar] = a1.z; As[ak + 7][ar] = a1.w;
    *(float4*)&Bsh[bk][bc] = b0;
    *(float4*)&Bsh[bk][bc + 4] = b1v;
    __syncthreads();
#pragma unroll
    for (int kk = 0; kk < 16; ++kk) {
      float4 aA = *(const float4*)&As[kk][ty * 4];
      float4 aB = *(const float4*)&As[kk][64 + ty * 4];
      float4 bA = *(const float4*)&Bsh[kk][tx * 4];
      float4 bB = *(const float4*)&Bsh[kk][64 + tx * 4];
      float av[2][4] = {{aA.x, aA.y, aA.z, aA.w}, {aB.x, aB.y, aB.z, aB.w}};
      float bv[2][4] = {{bA.x, bA.y, bA.z, bA.w}, {bB.x, bB.y, bB.z, bB.w}};
#pragma unroll
      for (int ri = 0; ri < 2; ++ri)
#pragma unroll
        for (int i = 0; i < 4; ++i)
#pragma unroll
          for (int rj = 0; rj < 2; ++rj)
#pragma unroll
            for (int j = 0; j < 4; ++j)
              acc[ri][rj][i][j] = fmaf(av[ri][i], bv[rj][j], acc[ri][rj][i][j]);
    }
  }
#pragma unroll
  for (int ri = 0; ri < 2; ++ri)
#pragma unroll
    for (int i = 0; i < 4; ++i) {
      int row = m0 + ri * 64 + ty * 4 + i;
#pragma unroll
      for (int rj = 0; rj < 2; ++rj) {
        int col = n0 + rj * 64 + tx * 4;
        float4 o;
        o.x = fmaxf(acc[ri][rj][i][0] + bias[col + 0], 0.f);
        o.y = fmaxf(acc[ri][rj][i][1] + bias[col + 1], 0.f);
        o.z = fmaxf(acc[ri][rj][i][2] + bias[col + 2], 0.f);
        o.w = fmaxf(acc[ri][rj][i][3] + bias[col + 3], 0.f);
        *(float4*)(C + (size_t)row * 1024 + col) = o;
      }
    }
}

// ---------------- K2: ner = C1 @ W2T^T + b2; softmax; argmax ----------------
__global__ __launch_bounds__(256) void k_ner(const float* __restrict__ C1,
                                             const float* __restrict__ W2T,
                                             const float* __restrict__ b2,
                                             float* __restrict__ ner_out,
                                             float* __restrict__ softm,
                                             int* __restrict__ amax) {
  const int wave = threadIdx.x >> 6, lane = threadIdx.x & 63;
  const int row0 = blockIdx.x * 16 + wave * 4;
  float acc[4][17];
#pragma unroll
  for (int r = 0; r < 4; ++r)
#pragma unroll
    for (int c = 0; c < 17; ++c) acc[r][c] = 0.f;
  for (int kb = 0; kb < 16; ++kb) {
    int k = kb * 64 + lane;
    float w2l[17];
#pragma unroll
    for (int c = 0; c < 17; ++c) w2l[c] = W2T[c * 1024 + k];
#pragma unroll
    for (int r = 0; r < 4; ++r) {
      float v = C1[(size_t)(row0 + r) * 1024 + k];
#pragma unroll
      for (int c = 0; c < 17; ++c) acc[r][c] = fmaf(v, w2l[c], acc[r][c]);
    }
  }
#pragma unroll
  for (int off = 32; off > 0; off >>= 1) {
#pragma unroll
    for (int r = 0; r < 4; ++r)
#pragma unroll
      for (int c = 0; c < 17; ++c) acc[r][c] += __shfl_xor(acc[r][c], off);
  }
  if (lane < 4) {
    const int row = row0 + lane;
    float v[17];
#pragma unroll
    for (int c = 0; c < 17; ++c) v[c] = acc[lane][c] + b2[c];
    float mx = v[0]; int am = 0;
#pragma unroll
    for (int c = 1; c < 17; ++c) { if (v[c] > mx) { mx = v[c]; am = c; } }
    float s = 0.f, e[17];
#pragma unroll
    for (int c = 0; c < 17; ++c) { e[c] = __expf(v[c] - mx); s += e[c]; }
    const float inv = 1.f / s;
    float* sm = softm + (size_t)row * 17;
#pragma unroll
    for (int c = 0; c < 17; ++c) sm[c] = e[c] * inv;
    amax[row] = am;
    const int b = row >> 10, sidx = row & 1023;
    if (sidx >= 1) {
      float* no = ner_out + ((size_t)b * SMM + sidx - 1) * 17;
#pragma unroll
      for (int c = 0; c < 17; ++c) no[c] = v[c];
    }
  }
}

// ---------------- K3: span logic + entity selection + pos_pairs ----------------
__global__ __launch_bounds__(64) void k_spans(const int* __restrict__ amax,
                                              int* __restrict__ meta,
                                              float* __restrict__ pp_out) {
  const int b = blockIdx.x, lane = threadIdx.x;
  __shared__ int nextE[4][1023];
  __shared__ int slist[4][10], blj[4][10], ble[4][10];
  __shared__ int ns[4], nb[4];
  __shared__ int posq[10];
  const int* am = amax + b * 1024 + 1;
  if (lane < 4) {
    const int t = lane;
    int cur = SMM;
    for (int j = SMM - 1; j >= 0; --j) {
      nextE[t][j] = cur;
      if (am[j] == 3 + 4 * t) cur = j;
    }
    int end = -1, cs = 0, cb = 0;
    for (int j = 0; j < SMM; ++j) {
      int a = am[j];
      if (a == 4 + 4 * t && cs < 10) slist[t][cs++] = j;
      if (a == 1 + 4 * t && j > end) {
        end = nextE[t][j];
        if (cb < 10) { blj[t][cb] = j; ble[t][cb] = end; cb++; }
      }
    }
    ns[t] = cs; nb[t] = cb;
  }
  __syncthreads();
  if (lane == 0) {
    int q = 0;
    for (int t = 0; t < 4 && q < 10; ++t) {
      for (int s = 0; s < ns[t] && q < 10; ++s) {
        int j = slist[t][s];
        int* m = meta + (b * 10 + q) * 4;
        m[0] = j; m[1] = j + 1; m[2] = 1; m[3] = 1;
        posq[q] = j + 1; ++q;
      }
      for (int s = 0; s < nb[t] && q < 10; ++s) {
        int j = blj[t][s], e = ble[t][s];
        int* m = meta + (b * 10 + q) * 4;
        m[0] = j; m[1] = e; m[2] = e - j; m[3] = 1;
        posq[q] = e + 1; ++q;
      }
    }
    for (; q < 10; ++q) {
      int* m = meta + (b * 10 + q) * 4;
      m[0] = 0; m[1] = 0; m[2] = 1; m[3] = 0;
      posq[q] = -1;
    }
  }
  __syncthreads();
  for (int pr = lane; pr < NPAIR; pr += 64) {
    int i = pr / 9, jj = pr % 9;
    int j = jj + (jj >= i ? 1 : 0);
    pp_out[(size_t)(b * NPAIR + pr) * 2 + 0] = (float)posq[i];
    pp_out[(size_t)(b * NPAIR + pr) * 2 + 1] = (float)posq[j];
  }
}

// ---------------- K4: ents = segment means ----------------
__global__ __launch_bounds__(256) void k_ents(const float* __restrict__ h,
                                              const float* __restrict__ softm,
                                              const int* __restrict__ meta,
                                              float* __restrict__ ents) {
  const int bq = blockIdx.x;
  const int b = bq / 10;
  const int* m = meta + bq * 4;
  const int j0 = m[0], e = m[1], len = m[2], vs = m[3];
  float acc[5] = {0.f, 0.f, 0.f, 0.f, 0.f};
  for (int row = j0; row < e; ++row) {
    const int s = row + 1;
    const float* hr = h + (size_t)(b * 1024 + s) * 1024;
    const float* sr = softm + (size_t)(b * 1024 + s) * 17;
#pragma unroll
    for (int i = 0; i < 5; ++i) {
      int d = threadIdx.x + i * 256;
      if (d < DXX) acc[i] += (d < 1024 ? hr[d] : sr[d - 1024]);
    }
  }
  const float inv = vs ? (1.0f / (float)len) : 0.0f;
#pragma unroll
  for (int i = 0; i < 5; ++i) {
    int d = threadIdx.x + i * 256;
    if (d < DXX) ents[(size_t)bq * DXX + d] = acc[i] * inv;
  }
}

// ---------------- K5: generic small GEMM ----------------
__global__ __launch_bounds__(256) void k_mlp(const float* __restrict__ A,
                                             const float* __restrict__ Bm,
                                             const float* __restrict__ bias,
                                             float* __restrict__ C,
                                             int M, int N, int K, int dorelu,
                                             long long bzs, long long czs) {
  const float* Bz = Bm + (size_t)blockIdx.z * bzs;
  float* Cz = C + (size_t)blockIdx.z * czs;
  __shared__ float As[16][64];
  const int n = blockIdx.x * 64 + (threadIdx.x & 63);
  const int rg = threadIdx.x >> 6;
  const int r0 = blockIdx.y * 16 + rg * 4;
  float acc[4] = {0.f, 0.f, 0.f, 0.f};
  for (int k0 = 0; k0 < K; k0 += 64) {
    __syncthreads();
    for (int idx = threadIdx.x; idx < 16 * 64; idx += 256) {
      int r = idx >> 6, kk = idx & 63;
      int k = k0 + kk;
      int row = blockIdx.y * 16 + r;
      As[r][kk] = (k < K && row < M) ? A[(size_t)row * K + k] : 0.f;
    }
    __syncthreads();
    int kmax = (K - k0 < 64) ? (K - k0) : 64;
    for (int kk = 0; kk < kmax; ++kk) {
      float bv = Bz[(size_t)(k0 + kk) * N + n];
#pragma unroll
      for (int i = 0; i < 4; ++i) acc[i] = fmaf(As[rg * 4 + i][kk], bv, acc[i]);
    }
  }
  float bb = bias ? bias[n] : 0.f;
#pragma unroll
  for (int i = 0; i < 4; ++i) {
    int row = r0 + i;
    if (row < M) {
      float v = acc[i] + bb;
      if (dorelu) v = fmaxf(v, 0.f);
      Cz[(size_t)row * N + n] = v;
    }
  }
}

// ---------------- K6: lh/lt = head/tail @ Wlin parts ----------------
__global__ __launch_bounds__(64) void k_lin(const float* __restrict__ headp,
                                            const float* __restrict__ tailp,
                                            const float* __restrict__ Wlin,
                                            float* __restrict__ lh,
                                            float* __restrict__ lt) {
  const int r = blockIdx.x, l = threadIdx.x;
  float a[16], bacc[16];
#pragma unroll
  for (int o = 0; o < 16; ++o) { a[o] = 0.f; bacc[o] = 0.f; }
  for (int k = l; k < 512; k += 64) {
    float hv = headp[(size_t)r * 512 + k];
    float tv = tailp[(size_t)r * 512 + k];
#pragma unroll
    for (int o = 0; o < 16; ++o) {
      a[o] = fmaf(hv, Wlin[o * 1024 + k], a[o]);
      bacc[o] = fmaf(tv, Wlin[o * 1024 + 512 + k], bacc[o]);
    }
  }
#pragma unroll
  for (int off = 32; off > 0; off >>= 1) {
#pragma unroll
    for (int o = 0; o < 16; ++o) {
      a[o] += __shfl_xor(a[o], off);
      bacc[o] += __shfl_xor(bacc[o], off);
    }
  }
  if (l == 0) {
#pragma unroll
    for (int o = 0; o < 16; ++o) {
      lh[r * 16 + o] = a[o];
      lt[r * 16 + o] = bacc[o];
    }
  }
}

// ---------------- K7: re ----------------
__global__ __launch_bounds__(256) void k_re(const float* __restrict__ u,
                                            const float* __restrict__ tailp,
                                            const float* __restrict__ lh,
                                            const float* __restrict__ lt,
                                            const float* __restrict__ bbil,
                                            float* __restrict__ re_out) {
  const int bp = blockIdx.x;
  const int b = bp / NPAIR, pr = bp % NPAIR;
  const int i = pr / 9, jj = pr % 9;
  const int j = jj + (jj >= i ? 1 : 0);
  const int wave = threadIdx.x >> 6, lane = threadIdx.x & 63;
  const float* tj = tailp + (size_t)(b * 10 + j) * 512;
#pragma unroll
  for (int oo = 0; oo < 4; ++oo) {
    const int o = wave + oo * 4;
    const float* uo = u + ((size_t)o * 320 + b * 10 + i) * 512;
    float acc = 0.f;
    for (int k = lane; k < 512; k += 64) acc = fmaf(uo[k], tj[k], acc);
#pragma unroll
    for (int off = 32; off > 0; off >>= 1) acc += __shfl_xor(acc, off);
    if (lane == 0)
      re_out[(size_t)bp * 16 + o] = acc + bbil[o] + lh[(b * 10 + i) * 16 + o] + lt[(b * 10 + j) * 16 + o];
  }
}

// ---------------- launch ----------------
extern "C" void kernel_launch(void* const* d_in, const int* in_sizes, int n_in,
                              void* d_out, int out_size, void* d_ws, size_t ws_size,
                              hipStream_t stream) {
  const float* h    = (const float*)d_in[0];
  const float* W1   = (const float*)d_in[1];
  const float* b1   = (const float*)d_in[2];
  const float* W2   = (const float*)d_in[3];
  const float* b2   = (const float*)d_in[4];
  const float* Wh1  = (const float*)d_in[5];
  const float* bh1  = (const float*)d_in[6];
  const float* Wh2  = (const float*)d_in[7];
  const float* bh2  = (const float*)d_in[8];
  const float* Wt1  = (const float*)d_in[9];
  const float* bt1  = (const float*)d_in[10];
  const float* Wt2  = (const float*)d_in[11];
  const float* bt2  = (const float*)d_in[12];
  const float* Wbil = (const float*)d_in[13];
  const float* bbil = (const float*)d_in[14];
  const float* Wlin = (const float*)d_in[15];

  float* out = (float*)d_out;
  float* ner_out = out;
  float* pp_out  = out + 556512;
  float* re_out  = out + 562272;

  char* ws = (char*)d_ws;
  float* C1    = (float*)(ws + 0);            // 134217728
  float* softm = (float*)(ws + 134217728);    // 2228224
  int*   amax  = (int*)  (ws + 136445952);    // 131072
  int*   meta  = (int*)  (ws + 136577024);    // 5120
  float* ents  = (float*)(ws + 136582144);    // 1332480
  float* H1    = (float*)(ws + 137914624);    // 655360
  float* T1    = (float*)(ws + 138569984);    // 655360
  float* headp = (float*)(ws + 139225344);    // 655360
  float* tailp = (float*)(ws + 139880704);    // 655360
  float* u     = (float*)(ws + 140536064);    // 10485760
  float* lh    = (float*)(ws + 151021824);    // 20480
  float* lt    = (float*)(ws + 151042304);    // 20480
  float* W2T   = (float*)(ws + 151062784);    // 69632
  unsigned short* wP = (unsigned short*)(ws + 151132416);   // 6291456
  unsigned short* hP = (unsigned short*)(ws + 157423872);   // 201326592
  const size_t NEED_FULL = 358750464;
  const size_t NEED_W2T  = 151132416;

  const bool full = ws_size >= NEED_FULL;
  const bool haveW2T = ws_size >= NEED_W2T;

  if (full) {
    k_split_h<<<2048, 256, 0, stream>>>((const float4*)h, (ushort4*)hP,
                                        (ushort4*)(hP + 33554432), (ushort4*)(hP + 67108864));
    k_split_w<<<dim3(32, 32), 256, 0, stream>>>(W1, wP);
    k_gemm1_mfma<<<dim3(8, 256), 256, 0, stream>>>(hP, wP, b1, C1);
  } else {
    k_gemm1<<<dim3(8, 256), 256, 0, stream>>>(h, W1, b1, C1);
  }
  if (haveW2T) {
    k_w2t<<<dim3(17, 4), 256, 0, stream>>>(W2, W2T);
    k_ner<<<2048, 256, 0, stream>>>(C1, W2T, b2, ner_out, softm, amax);
  } else {
    // degenerate: reuse softm area is not possible; fall back to strided reads via W2T==W2 trick
    // (should not happen: prior round ran with ws >= 151 MB)
    k_w2t<<<dim3(17, 4), 256, 0, stream>>>(W2, (float*)(ws + 140536064)); // overwrite u temporarily-safe? no-op guard
    k_ner<<<2048, 256, 0, stream>>>(C1, (float*)(ws + 140536064), b2, ner_out, softm, amax);
  }
  k_spans<<<32, 64, 0, stream>>>(amax, meta, pp_out);
  k_ents<<<320, 256, 0, stream>>>(h, softm, meta, ents);
  k_mlp<<<dim3(8, 20, 1), 256, 0, stream>>>(ents, Wh1, bh1, H1, 320, 512, 1041, 1, 0, 0);
  k_mlp<<<dim3(8, 20, 1), 256, 0, stream>>>(H1, Wh2, bh2, headp, 320, 512, 512, 0, 0, 0);
  k_mlp<<<dim3(8, 20, 1), 256, 0, stream>>>(ents, Wt1, bt1, T1, 320, 512, 1041, 1, 0, 0);
  k_mlp<<<dim3(8, 20, 1), 256, 0, stream>>>(T1, Wt2, bt2, tailp, 320, 512, 512, 0, 0, 0);
  k_mlp<<<dim3(8, 20, 16), 256, 0, stream>>>(headp, Wbil, nullptr, u, 320, 512, 512, 0,
                                             (long long)512 * 512, (long long)320 * 512);
  k_lin<<<320, 64, 0, stream>>>(headp, tailp, Wlin, lh, lt);
  k_re<<<2880, 256, 0, stream>>>(u, tailp, lh, lt, bbil, re_out);
}

// Round 3
// 1386.672 us; speedup vs baseline: 1.2946x; 1.1624x over previous
//
#include <hip/hip_runtime.h>
#include <hip/hip_bf16.h>

// ---------------- constants ----------------
#define BB   32
#define SS   1024
#define DD   1024
#define SMM  1023
#define NER  17
#define HH   512
#define DXX  1041
#define PP   10
#define NPAIR 90

typedef __bf16 bf16x8 __attribute__((ext_vector_type(8)));
typedef float f32x4 __attribute__((ext_vector_type(4)));

// ---------------- split helpers ----------------
__device__ inline void split3(float x, unsigned short& s0, unsigned short& s1, unsigned short& s2) {
  __hip_bfloat16 h0 = __float2bfloat16(x);
  float f0 = __bfloat162float(h0);
  float r1 = x - f0;
  __hip_bfloat16 h1 = __float2bfloat16(r1);
  float f1 = __bfloat162float(h1);
  float r2 = r1 - f1;
  __hip_bfloat16 h2 = __float2bfloat16(r2);
  s0 = *reinterpret_cast<unsigned short*>(&h0);
  s1 = *reinterpret_cast<unsigned short*>(&h1);
  s2 = *reinterpret_cast<unsigned short*>(&h2);
}

// ---------------- K0a: split h into 3 bf16 planes ----------------
__global__ __launch_bounds__(256) void k_split_h(const float4* __restrict__ h4,
                                                 ushort4* __restrict__ p0,
                                                 ushort4* __restrict__ p1,
                                                 ushort4* __restrict__ p2) {
  const int idx = blockIdx.x * 256 + threadIdx.x;
  for (int i = idx; i < 8388608; i += 524288) {
    float4 v = h4[i];
    ushort4 a, b, c;
    split3(v.x, a.x, b.x, c.x);
    split3(v.y, a.y, b.y, c.y);
    split3(v.z, a.z, b.z, c.z);
    split3(v.w, a.w, b.w, c.w);
    p0[i] = a; p1[i] = b; p2[i] = c;
  }
}

// ---------------- K0b: split + transpose W1 -> 3 bf16 planes of W1^T [n][k] ----------------
__global__ __launch_bounds__(256) void k_split_w(const float* __restrict__ W,
                                                 unsigned short* __restrict__ wP) {
  __shared__ float t[32][33];
  const int bk = blockIdx.x * 32, bn = blockIdx.y * 32;
  const int tr = threadIdx.x >> 5, tc = threadIdx.x & 31;
#pragma unroll
  for (int i = 0; i < 4; ++i)
    t[tr + i * 8][tc] = W[(size_t)(bk + tr + i * 8) * 1024 + bn + tc];
  __syncthreads();
#pragma unroll
  for (int i = 0; i < 4; ++i) {
    const int n = bn + tr + i * 8, k = bk + tc;
    unsigned short s0, s1, s2;
    split3(t[tc][tr + i * 8], s0, s1, s2);
    wP[(size_t)n * 1024 + k] = s0;
    wP[1048576 + (size_t)n * 1024 + k] = s1;
    wP[2097152 + (size_t)n * 1024 + k] = s2;
  }
}

// ---------------- K0c: transpose W2 -> W2T[17][1024] ----------------
__global__ void k_w2t(const float* __restrict__ W2, float* __restrict__ W2T) {
  const int c = blockIdx.x, k = blockIdx.y * 256 + threadIdx.x;
  W2T[c * 1024 + k] = W2[k * 17 + c];
}

// ---------------- K1 (MFMA): C1 = relu(h@W1 + b1), bf16x3 6-product, XCD-swizzled ----------------
__global__ __launch_bounds__(256) void k_gemm1_mfma(const unsigned short* __restrict__ hP,
                                                    const unsigned short* __restrict__ wP,
                                                    const float* __restrict__ bias,
                                                    float* __restrict__ C) {
  __shared__ unsigned short As[128 * 64];
  __shared__ unsigned short Bs[128 * 64];
  const int tid = threadIdx.x;
  const int w = tid >> 6, l = tid & 63;
  // T1: XCD-chunk swizzle. nwg=2048, 8 XCDs -> each XCD owns a contiguous
  // 256-block chunk = 32 m-tiles x 8 n-tiles; A-panel (1.5 MB) reused 8x in its L2.
  const int bid = blockIdx.x;
  const int wid = (bid & 7) * 256 + (bid >> 3);
  const int m0 = (wid >> 3) * 128;
  const int n0 = (wid & 7) * 128;
  const int lo3 = l & 7;
  const int ksw = ((l & 7) ^ ((l >> 3) & 7)) * 8;  // pre-swizzled global k offset (elements)
  const int rbase = w * 8 + (l >> 3);              // + i*32 -> LDS row
  const int wm = w & 1, wn = w >> 1;
  const int trA = wm * 64 + (l & 15);
  const int trB = wn * 64 + (l & 15);
  const int slotbase = l >> 4;
  f32x4 acc[4][4];
#pragma unroll
  for (int i = 0; i < 4; ++i)
#pragma unroll
    for (int j = 0; j < 4; ++j) acc[i][j] = (f32x4){0.f, 0.f, 0.f, 0.f};

  // segment plane selectors: s=0..5 -> (a,b) = (2,0)(1,1)(0,2)(1,0)(0,1)(0,0), small terms first
  const unsigned saBits = 2u | (1u << 2) | (0u << 4) | (1u << 6) | (0u << 8) | (0u << 10);
  const unsigned sbBits = 0u | (1u << 2) | (2u << 4) | (0u << 6) | (1u << 8) | (0u << 10);

  for (int step = 0; step < 96; ++step) {
    const int s = step >> 4;
    const int k0 = (step & 15) << 6;
    const int pa = (saBits >> (2 * s)) & 3;
    const int pb = (sbBits >> (2 * s)) & 3;
    const unsigned short* Ab = hP + (size_t)pa * 33554432 + k0 + ksw;
    const unsigned short* Bb = wP + (size_t)pb * 1048576 + k0 + ksw;
#pragma unroll
    for (int i = 0; i < 4; ++i) {
      const int row = rbase + i * 32;
      __builtin_amdgcn_global_load_lds(
          (const __attribute__((address_space(1))) void*)(Ab + (size_t)(m0 + row) * 1024),
          (__attribute__((address_space(3))) void*)((char*)As + i * 4096 + w * 1024 + (l & 63) * 16),
          16, 0, 0);
    }
#pragma unroll
    for (int i = 0; i < 4; ++i) {
      const int row = rbase + i * 32;
      __builtin_amdgcn_global_load_lds(
          (const __attribute__((address_space(1))) void*)(Bb + (size_t)(n0 + row) * 1024),
          (__attribute__((address_space(3))) void*)((char*)Bs + i * 4096 + w * 1024 + (l & 63) * 16),
          16, 0, 0);
    }
    __syncthreads();
#pragma unroll
    for (int kk2 = 0; kk2 < 2; ++kk2) {
      bf16x8 af[4], bfr[4];
#pragma unroll
      for (int m = 0; m < 4; ++m) {
        const int row = trA + m * 16;
        const int byte = row * 128 + ((((kk2 << 2) + slotbase) ^ lo3) << 4);
        af[m] = *(const bf16x8*)((const char*)As + byte);
      }
#pragma unroll
      for (int n = 0; n < 4; ++n) {
        const int row = trB + n * 16;
        const int byte = row * 128 + ((((kk2 << 2) + slotbase) ^ lo3) << 4);
        bfr[n] = *(const bf16x8*)((const char*)Bs + byte);
      }
#pragma unroll
      for (int m = 0; m < 4; ++m)
#pragma unroll
        for (int n = 0; n < 4; ++n)
          acc[m][n] = __builtin_amdgcn_mfma_f32_16x16x32_bf16(af[m], bfr[n], acc[m][n], 0, 0, 0);
    }
    __syncthreads();
  }
  const int crow0 = m0 + wm * 64 + (l >> 4) * 4;
  const int ccol0 = n0 + wn * 64 + (l & 15);
#pragma unroll
  for (int n = 0; n < 4; ++n) {
    const int col = ccol0 + n * 16;
    const float bb = bias[col];
#pragma unroll
    for (int m = 0; m < 4; ++m)
#pragma unroll
      for (int r = 0; r < 4; ++r) {
        const int row = crow0 + m * 16 + r;
        C[(size_t)row * 1024 + col] = fmaxf(acc[m][n][r] + bb, 0.f);
      }
  }
}

// ---------------- K1-fallback: fp32 vector GEMM (used when ws too small) ----------------
__global__ __launch_bounds__(256) void k_gemm1(const float* __restrict__ A,
                                               const float* __restrict__ Bm,
                                               const float* __restrict__ bias,
                                               float* __restrict__ C) {
  __shared__ float As[16][128];
  __shared__ float Bsh[16][128];
  const int tid = threadIdx.x;
  const int tx = tid & 15, ty = tid >> 4;
  const int n0 = blockIdx.x * 128, m0 = blockIdx.y * 128;
  const int ar = tid >> 1, ak = (tid & 1) * 8;
  const int bk = tid >> 4, bc = (tid & 15) * 8;
  float acc[2][2][4][4] = {};
  for (int k0 = 0; k0 < 1024; k0 += 16) {
    float4 a0 = *(const float4*)(A + (size_t)(m0 + ar) * 1024 + k0 + ak);
    float4 a1 = *(const float4*)(A + (size_t)(m0 + ar) * 1024 + k0 + ak + 4);
    float4 b0 = *(const float4*)(Bm + (size_t)(k0 + bk) * 1024 + n0 + bc);
    float4 b1v = *(const float4*)(Bm + (size_t)(k0 + bk) * 1024 + n0 + bc + 4);
    __syncthreads();
    As[ak + 0][ar] = a0.x; As[ak + 1][ar] = a0.y; As[ak + 2][ar] = a0.z; As[ak + 3][ar] = a0.w;
    As[ak + 4][ar] = a1.x; As[ak + 5][ar] = a1.y; As[ak + 6][ar] = a1.z; As[ak + 7][ar] = a1.w;
    *(float4*)&Bsh[bk][bc] = b0;
    *(float4*)&Bsh[bk][bc + 4] = b1v;
    __syncthreads();
#pragma unroll
    for (int kk = 0; kk < 16; ++kk) {
      float4 aA = *(const float4*)&As[kk][ty * 4];
      float4 aB = *(const float4*)&As[kk][64 + ty * 4];
      float4 bA = *(const float4*)&Bsh[kk][tx * 4];
      float4 bB = *(const float4*)&Bsh[kk][64 + tx * 4];
      float av[2][4] = {{aA.x, aA.y, aA.z, aA.w}, {aB.x, aB.y, aB.z, aB.w}};
      float bv[2][4] = {{bA.x, bA.y, bA.z, bA.w}, {bB.x, bB.y, bB.z, bB.w}};
#pragma unroll
      for (int ri = 0; ri < 2; ++ri)
#pragma unroll
        for (int i = 0; i < 4; ++i)
#pragma unroll
          for (int rj = 0; rj < 2; ++rj)
#pragma unroll
            for (int j = 0; j < 4; ++j)
              acc[ri][rj][i][j] = fmaf(av[ri][i], bv[rj][j], acc[ri][rj][i][j]);
    }
  }
#pragma unroll
  for (int ri = 0; ri < 2; ++ri)
#pragma unroll
    for (int i = 0; i < 4; ++i) {
      int row = m0 + ri * 64 + ty * 4 + i;
#pragma unroll
      for (int rj = 0; rj < 2; ++rj) {
        int col = n0 + rj * 64 + tx * 4;
        float4 o;
        o.x = fmaxf(acc[ri][rj][i][0] + bias[col + 0], 0.f);
        o.y = fmaxf(acc[ri][rj][i][1] + bias[col + 1], 0.f);
        o.z = fmaxf(acc[ri][rj][i][2] + bias[col + 2], 0.f);
        o.w = fmaxf(acc[ri][rj][i][3] + bias[col + 3], 0.f);
        *(float4*)(C + (size_t)row * 1024 + col) = o;
      }
    }
}

// ---------------- K2: ner = C1 @ W2T^T + b2; softmax; argmax ----------------
__global__ __launch_bounds__(256) void k_ner(const float* __restrict__ C1,
                                             const float* __restrict__ W2T,
                                             const float* __restrict__ b2,
                                             float* __restrict__ ner_out,
                                             float* __restrict__ softm,
                                             int* __restrict__ amax) {
  const int wave = threadIdx.x >> 6, lane = threadIdx.x & 63;
  const int row0 = blockIdx.x * 16 + wave * 4;
  float acc[4][17];
#pragma unroll
  for (int r = 0; r < 4; ++r)
#pragma unroll
    for (int c = 0; c < 17; ++c) acc[r][c] = 0.f;
  for (int kb = 0; kb < 16; ++kb) {
    int k = kb * 64 + lane;
    float w2l[17];
#pragma unroll
    for (int c = 0; c < 17; ++c) w2l[c] = W2T[c * 1024 + k];
#pragma unroll
    for (int r = 0; r < 4; ++r) {
      float v = C1[(size_t)(row0 + r) * 1024 + k];
#pragma unroll
      for (int c = 0; c < 17; ++c) acc[r][c] = fmaf(v, w2l[c], acc[r][c]);
    }
  }
#pragma unroll
  for (int off = 32; off > 0; off >>= 1) {
#pragma unroll
    for (int r = 0; r < 4; ++r)
#pragma unroll
      for (int c = 0; c < 17; ++c) acc[r][c] += __shfl_xor(acc[r][c], off);
  }
  if (lane < 4) {
    const int row = row0 + lane;
    float v[17];
#pragma unroll
    for (int c = 0; c < 17; ++c) v[c] = acc[lane][c] + b2[c];
    float mx = v[0]; int am = 0;
#pragma unroll
    for (int c = 1; c < 17; ++c) { if (v[c] > mx) { mx = v[c]; am = c; } }
    float s = 0.f, e[17];
#pragma unroll
    for (int c = 0; c < 17; ++c) { e[c] = __expf(v[c] - mx); s += e[c]; }
    const float inv = 1.f / s;
    float* sm = softm + (size_t)row * 17;
#pragma unroll
    for (int c = 0; c < 17; ++c) sm[c] = e[c] * inv;
    amax[row] = am;
    const int b = row >> 10, sidx = row & 1023;
    if (sidx >= 1) {
      float* no = ner_out + ((size_t)b * SMM + sidx - 1) * 17;
#pragma unroll
      for (int c = 0; c < 17; ++c) no[c] = v[c];
    }
  }
}

// ---------------- K3: span logic + entity selection + pos_pairs ----------------
__global__ __launch_bounds__(64) void k_spans(const int* __restrict__ amax,
                                              int* __restrict__ meta,
                                              float* __restrict__ pp_out) {
  const int b = blockIdx.x, lane = threadIdx.x;
  __shared__ int nextE[4][1023];
  __shared__ int slist[4][10], blj[4][10], ble[4][10];
  __shared__ int ns[4], nb[4];
  __shared__ int posq[10];
  const int* am = amax + b * 1024 + 1;
  if (lane < 4) {
    const int t = lane;
    int cur = SMM;
    for (int j = SMM - 1; j >= 0; --j) {
      nextE[t][j] = cur;
      if (am[j] == 3 + 4 * t) cur = j;
    }
    int end = -1, cs = 0, cb = 0;
    for (int j = 0; j < SMM; ++j) {
      int a = am[j];
      if (a == 4 + 4 * t && cs < 10) slist[t][cs++] = j;
      if (a == 1 + 4 * t && j > end) {
        end = nextE[t][j];
        if (cb < 10) { blj[t][cb] = j; ble[t][cb] = end; cb++; }
      }
    }
    ns[t] = cs; nb[t] = cb;
  }
  __syncthreads();
  if (lane == 0) {
    int q = 0;
    for (int t = 0; t < 4 && q < 10; ++t) {
      for (int s = 0; s < ns[t] && q < 10; ++s) {
        int j = slist[t][s];
        int* m = meta + (b * 10 + q) * 4;
        m[0] = j; m[1] = j + 1; m[2] = 1; m[3] = 1;
        posq[q] = j + 1; ++q;
      }
      for (int s = 0; s < nb[t] && q < 10; ++s) {
        int j = blj[t][s], e = ble[t][s];
        int* m = meta + (b * 10 + q) * 4;
        m[0] = j; m[1] = e; m[2] = e - j; m[3] = 1;
        posq[q] = e + 1; ++q;
      }
    }
    for (; q < 10; ++q) {
      int* m = meta + (b * 10 + q) * 4;
      m[0] = 0; m[1] = 0; m[2] = 1; m[3] = 0;
      posq[q] = -1;
    }
  }
  __syncthreads();
  for (int pr = lane; pr < NPAIR; pr += 64) {
    int i = pr / 9, jj = pr % 9;
    int j = jj + (jj >= i ? 1 : 0);
    pp_out[(size_t)(b * NPAIR + pr) * 2 + 0] = (float)posq[i];
    pp_out[(size_t)(b * NPAIR + pr) * 2 + 1] = (float)posq[j];
  }
}

// ---------------- K4: ents = segment means ----------------
__global__ __launch_bounds__(256) void k_ents(const float* __restrict__ h,
                                              const float* __restrict__ softm,
                                              const int* __restrict__ meta,
                                              float* __restrict__ ents) {
  const int bq = blockIdx.x;
  const int b = bq / 10;
  const int* m = meta + bq * 4;
  const int j0 = m[0], e = m[1], len = m[2], vs = m[3];
  float acc[5] = {0.f, 0.f, 0.f, 0.f, 0.f};
  for (int row = j0; row < e; ++row) {
    const int s = row + 1;
    const float* hr = h + (size_t)(b * 1024 + s) * 1024;
    const float* sr = softm + (size_t)(b * 1024 + s) * 17;
#pragma unroll
    for (int i = 0; i < 5; ++i) {
      int d = threadIdx.x + i * 256;
      if (d < DXX) acc[i] += (d < 1024 ? hr[d] : sr[d - 1024]);
    }
  }
  const float inv = vs ? (1.0f / (float)len) : 0.0f;
#pragma unroll
  for (int i = 0; i < 5; ++i) {
    int d = threadIdx.x + i * 256;
    if (d < DXX) ents[(size_t)bq * DXX + d] = acc[i] * inv;
  }
}

// ---------------- K5a: fused head/tail layer-1 (relu(ents@W+b)), 512 thr, 2 rows/blk ----------------
__global__ __launch_bounds__(512) void k_mlp_l1(const float* __restrict__ ents,
                                                const float* __restrict__ Wh1, const float* __restrict__ bh1,
                                                const float* __restrict__ Wt1, const float* __restrict__ bt1,
                                                float* __restrict__ H1, float* __restrict__ T1) {
  __shared__ float e[2][DXX];
  const int r0 = blockIdx.x * 2;
  const int chain = blockIdx.y;
  const float* W = chain ? Wt1 : Wh1;
  const float* bi = chain ? bt1 : bh1;
  float* out = chain ? T1 : H1;
  for (int idx = threadIdx.x; idx < 2 * DXX; idx += 512) {
    int row = idx >= DXX;
    int col = row ? idx - DXX : idx;
    e[row][col] = ents[(size_t)(r0 + row) * DXX + col];
  }
  __syncthreads();
  const int n = threadIdx.x;
  float a0 = 0.f, a1 = 0.f;
#pragma unroll 4
  for (int k = 0; k < DXX; ++k) {
    float w = W[(size_t)k * 512 + n];
    a0 = fmaf(e[0][k], w, a0);
    a1 = fmaf(e[1][k], w, a1);
  }
  const float bv = bi[n];
  out[(size_t)r0 * 512 + n] = fmaxf(a0 + bv, 0.f);
  out[(size_t)(r0 + 1) * 512 + n] = fmaxf(a1 + bv, 0.f);
}

// ---------------- K5b: fused head/tail layer-2 (X@W+b, no relu) ----------------
__global__ __launch_bounds__(512) void k_mlp_l2(const float* __restrict__ H1, const float* __restrict__ T1,
                                                const float* __restrict__ Wh2, const float* __restrict__ bh2,
                                                const float* __restrict__ Wt2, const float* __restrict__ bt2,
                                                float* __restrict__ headp, float* __restrict__ tailp) {
  __shared__ float e[2][512];
  const int r0 = blockIdx.x * 2;
  const int chain = blockIdx.y;
  const float* in = chain ? T1 : H1;
  const float* W = chain ? Wt2 : Wh2;
  const float* bi = chain ? bt2 : bh2;
  float* out = chain ? tailp : headp;
  for (int idx = threadIdx.x; idx < 1024; idx += 512)
    e[idx >> 9][idx & 511] = in[(size_t)r0 * 512 + idx];
  __syncthreads();
  const int n = threadIdx.x;
  float a0 = 0.f, a1 = 0.f;
#pragma unroll 4
  for (int k = 0; k < 512; ++k) {
    float w = W[(size_t)k * 512 + n];
    a0 = fmaf(e[0][k], w, a0);
    a1 = fmaf(e[1][k], w, a1);
  }
  const float bv = bi[n];
  out[(size_t)r0 * 512 + n] = a0 + bv;
  out[(size_t)(r0 + 1) * 512 + n] = a1 + bv;
}

// ---------------- K5c: bilinear u[o,i,:] = head[i,:] @ Wbil[o], 16 rows/blk ----------------
__global__ __launch_bounds__(512) void k_bil(const float* __restrict__ headp,
                                             const float* __restrict__ Wbil,
                                             float* __restrict__ u) {
  __shared__ float hs[16 * 512];
  const int m0 = blockIdx.x * 16;
  const int o = blockIdx.y;
  for (int idx = threadIdx.x; idx < 16 * 512; idx += 512)
    hs[idx] = headp[(size_t)m0 * 512 + idx];
  __syncthreads();
  const int n = threadIdx.x;
  const float* Wo = Wbil + (size_t)o * 262144;
  float acc[16];
#pragma unroll
  for (int i = 0; i < 16; ++i) acc[i] = 0.f;
  for (int k = 0; k < 512; ++k) {
    float w = Wo[(size_t)k * 512 + n];
#pragma unroll
    for (int i = 0; i < 16; ++i) acc[i] = fmaf(hs[i * 512 + k], w, acc[i]);
  }
#pragma unroll
  for (int i = 0; i < 16; ++i)
    u[((size_t)o * 320 + m0 + i) * 512 + n] = acc[i];
}

// ---------------- K6: lh/lt = head/tail @ Wlin parts (k-split over 4 waves) ----------------
__global__ __launch_bounds__(256) void k_lin(const float* __restrict__ headp,
                                             const float* __restrict__ tailp,
                                             const float* __restrict__ Wlin,
                                             float* __restrict__ lh,
                                             float* __restrict__ lt) {
  __shared__ float redH[4][16], redT[4][16];
  const int r = blockIdx.x;
  const int wv = threadIdx.x >> 6, lane = threadIdx.x & 63;
  const float* hr = headp + (size_t)r * 512;
  const float* tr = tailp + (size_t)r * 512;
  float a[16], bacc[16];
#pragma unroll
  for (int o = 0; o < 16; ++o) { a[o] = 0.f; bacc[o] = 0.f; }
#pragma unroll
  for (int kk = 0; kk < 2; ++kk) {
    const int k = wv * 128 + kk * 64 + lane;
    const float hv = hr[k], tv = tr[k];
#pragma unroll
    for (int o = 0; o < 16; ++o) {
      a[o] = fmaf(hv, Wlin[o * 1024 + k], a[o]);
      bacc[o] = fmaf(tv, Wlin[o * 1024 + 512 + k], bacc[o]);
    }
  }
#pragma unroll
  for (int off = 32; off > 0; off >>= 1) {
#pragma unroll
    for (int o = 0; o < 16; ++o) {
      a[o] += __shfl_xor(a[o], off);
      bacc[o] += __shfl_xor(bacc[o], off);
    }
  }
  if (lane == 0) {
#pragma unroll
    for (int o = 0; o < 16; ++o) { redH[wv][o] = a[o]; redT[wv][o] = bacc[o]; }
  }
  __syncthreads();
  if (threadIdx.x < 16) {
    const int o = threadIdx.x;
    float s = 0.f, t = 0.f;
#pragma unroll
    for (int w2 = 0; w2 < 4; ++w2) { s += redH[w2][o]; t += redT[w2][o]; }
    lh[r * 16 + o] = s;
    lt[r * 16 + o] = t;
  }
}

// ---------------- K7: re ----------------
__global__ __launch_bounds__(256) void k_re(const float* __restrict__ u,
                                            const float* __restrict__ tailp,
                                            const float* __restrict__ lh,
                                            const float* __restrict__ lt,
                                            const float* __restrict__ bbil,
                                            float* __restrict__ re_out) {
  const int bp = blockIdx.x;
  const int b = bp / NPAIR, pr = bp % NPAIR;
  const int i = pr / 9, jj = pr % 9;
  const int j = jj + (jj >= i ? 1 : 0);
  const int wave = threadIdx.x >> 6, lane = threadIdx.x & 63;
  const float* tj = tailp + (size_t)(b * 10 + j) * 512;
#pragma unroll
  for (int oo = 0; oo < 4; ++oo) {
    const int o = wave + oo * 4;
    const float* uo = u + ((size_t)o * 320 + b * 10 + i) * 512;
    float acc = 0.f;
    for (int k = lane; k < 512; k += 64) acc = fmaf(uo[k], tj[k], acc);
#pragma unroll
    for (int off = 32; off > 0; off >>= 1) acc += __shfl_xor(acc, off);
    if (lane == 0)
      re_out[(size_t)bp * 16 + o] = acc + bbil[o] + lh[(b * 10 + i) * 16 + o] + lt[(b * 10 + j) * 16 + o];
  }
}

// ---------------- launch ----------------
extern "C" void kernel_launch(void* const* d_in, const int* in_sizes, int n_in,
                              void* d_out, int out_size, void* d_ws, size_t ws_size,
                              hipStream_t stream) {
  const float* h    = (const float*)d_in[0];
  const float* W1   = (const float*)d_in[1];
  const float* b1   = (const float*)d_in[2];
  const float* W2   = (const float*)d_in[3];
  const float* b2   = (const float*)d_in[4];
  const float* Wh1  = (const float*)d_in[5];
  const float* bh1  = (const float*)d_in[6];
  const float* Wh2  = (const float*)d_in[7];
  const float* bh2  = (const float*)d_in[8];
  const float* Wt1  = (const float*)d_in[9];
  const float* bt1  = (const float*)d_in[10];
  const float* Wt2  = (const float*)d_in[11];
  const float* bt2  = (const float*)d_in[12];
  const float* Wbil = (const float*)d_in[13];
  const float* bbil = (const float*)d_in[14];
  const float* Wlin = (const float*)d_in[15];

  float* out = (float*)d_out;
  float* ner_out = out;
  float* pp_out  = out + 556512;
  float* re_out  = out + 562272;

  char* ws = (char*)d_ws;
  float* C1    = (float*)(ws + 0);            // 134217728
  float* softm = (float*)(ws + 134217728);    // 2228224
  int*   amax  = (int*)  (ws + 136445952);    // 131072
  int*   meta  = (int*)  (ws + 136577024);    // 5120
  float* ents  = (float*)(ws + 136582144);    // 1332480
  float* H1    = (float*)(ws + 137914624);    // 655360
  float* T1    = (float*)(ws + 138569984);    // 655360
  float* headp = (float*)(ws + 139225344);    // 655360
  float* tailp = (float*)(ws + 139880704);    // 655360
  float* u     = (float*)(ws + 140536064);    // 10485760
  float* lh    = (float*)(ws + 151021824);    // 20480
  float* lt    = (float*)(ws + 151042304);    // 20480
  float* W2T   = (float*)(ws + 151062784);    // 69632
  unsigned short* wP = (unsigned short*)(ws + 151132416);   // 6291456
  unsigned short* hP = (unsigned short*)(ws + 157423872);   // 201326592
  const size_t NEED_FULL = 358750464;
  const size_t NEED_W2T  = 151132416;

  const bool full = ws_size >= NEED_FULL;
  const bool haveW2T = ws_size >= NEED_W2T;

  if (full) {
    k_split_h<<<2048, 256, 0, stream>>>((const float4*)h, (ushort4*)hP,
                                        (ushort4*)(hP + 33554432), (ushort4*)(hP + 67108864));
    k_split_w<<<dim3(32, 32), 256, 0, stream>>>(W1, wP);
    k_gemm1_mfma<<<2048, 256, 0, stream>>>(hP, wP, b1, C1);
  } else {
    k_gemm1<<<dim3(8, 256), 256, 0, stream>>>(h, W1, b1, C1);
  }
  if (haveW2T) {
    k_w2t<<<dim3(17, 4), 256, 0, stream>>>(W2, W2T);
    k_ner<<<2048, 256, 0, stream>>>(C1, W2T, b2, ner_out, softm, amax);
  } else {
    k_w2t<<<dim3(17, 4), 256, 0, stream>>>(W2, (float*)(ws + 140536064));
    k_ner<<<2048, 256, 0, stream>>>(C1, (float*)(ws + 140536064), b2, ner_out, softm, amax);
  }
  k_spans<<<32, 64, 0, stream>>>(amax, meta, pp_out);
  k_ents<<<320, 256, 0, stream>>>(h, softm, meta, ents);
  k_mlp_l1<<<dim3(160, 2), 512, 0, stream>>>(ents, Wh1, bh1, Wt1, bt1, H1, T1);
  k_mlp_l2<<<dim3(160, 2), 512, 0, stream>>>(H1, T1, Wh2, bh2, Wt2, bt2, headp, tailp);
  k_bil<<<dim3(20, 16), 512, 0, stream>>>(headp, Wbil, u);
  k_lin<<<320, 256, 0, stream>>>(headp, tailp, Wlin, lh, lt);
  k_re<<<2880, 256, 0, stream>>>(u, tailp, lh, lt, bbil, re_out);
}

// Round 4
// 1251.558 us; speedup vs baseline: 1.4343x; 1.1080x over previous
//
#include <hip/hip_runtime.h>
#include <hip/hip_bf16.h>

// ---------------- constants ----------------
#define BB   32
#define SS   1024
#define DD   1024
#define SMM  1023
#define NER  17
#define HH   512
#define DXX  1041
#define PP   10
#define NPAIR 90

typedef __bf16 bf16x8 __attribute__((ext_vector_type(8)));
typedef float f32x4 __attribute__((ext_vector_type(4)));

#define VMCNT(n) asm volatile("s_waitcnt vmcnt(" #n ")" ::: "memory")
#define BAR_MEM() asm volatile("s_barrier" ::: "memory")

// segment plane selectors: s=0..5 -> (a,b) = (2,0)(1,1)(0,2)(1,0)(0,1)(0,0), small terms first
#define SA_BITS (2u | (1u << 2) | (0u << 4) | (1u << 6) | (0u << 8) | (0u << 10))
#define SB_BITS (0u | (1u << 2) | (2u << 4) | (0u << 6) | (1u << 8) | (0u << 10))

// ---------------- split helpers ----------------
__device__ inline void split3(float x, unsigned short& s0, unsigned short& s1, unsigned short& s2) {
  __hip_bfloat16 h0 = __float2bfloat16(x);
  float f0 = __bfloat162float(h0);
  float r1 = x - f0;
  __hip_bfloat16 h1 = __float2bfloat16(r1);
  float f1 = __bfloat162float(h1);
  float r2 = r1 - f1;
  __hip_bfloat16 h2 = __float2bfloat16(r2);
  s0 = *reinterpret_cast<unsigned short*>(&h0);
  s1 = *reinterpret_cast<unsigned short*>(&h1);
  s2 = *reinterpret_cast<unsigned short*>(&h2);
}

// ---------------- K0a: split h into 3 bf16 planes ----------------
__global__ __launch_bounds__(256) void k_split_h(const float4* __restrict__ h4,
                                                 ushort4* __restrict__ p0,
                                                 ushort4* __restrict__ p1,
                                                 ushort4* __restrict__ p2) {
  const int idx = blockIdx.x * 256 + threadIdx.x;
  for (int i = idx; i < 8388608; i += 524288) {
    float4 v = h4[i];
    ushort4 a, b, c;
    split3(v.x, a.x, b.x, c.x);
    split3(v.y, a.y, b.y, c.y);
    split3(v.z, a.z, b.z, c.z);
    split3(v.w, a.w, b.w, c.w);
    p0[i] = a; p1[i] = b; p2[i] = c;
  }
}

// ---------------- K0b: split + transpose W1 -> 3 bf16 planes of W1^T [n][k] ----------------
__global__ __launch_bounds__(256) void k_split_w(const float* __restrict__ W,
                                                 unsigned short* __restrict__ wP) {
  __shared__ float t[32][33];
  const int bk = blockIdx.x * 32, bn = blockIdx.y * 32;
  const int tr = threadIdx.x >> 5, tc = threadIdx.x & 31;
#pragma unroll
  for (int i = 0; i < 4; ++i)
    t[tr + i * 8][tc] = W[(size_t)(bk + tr + i * 8) * 1024 + bn + tc];
  __syncthreads();
#pragma unroll
  for (int i = 0; i < 4; ++i) {
    const int n = bn + tr + i * 8, k = bk + tc;
    unsigned short s0, s1, s2;
    split3(t[tc][tr + i * 8], s0, s1, s2);
    wP[(size_t)n * 1024 + k] = s0;
    wP[1048576 + (size_t)n * 1024 + k] = s1;
    wP[2097152 + (size_t)n * 1024 + k] = s2;
  }
}

// ---------------- K0c: transpose W2 -> W2T[17][1024] ----------------
__global__ void k_w2t(const float* __restrict__ W2, float* __restrict__ W2T) {
  const int c = blockIdx.x, k = blockIdx.y * 256 + threadIdx.x;
  W2T[c * 1024 + k] = W2[k * 17 + c];
}

// ---------------- K1: 256x256 8-phase MFMA GEMM, bf16x3 6-product, K'=6144 ----------------
// 512 threads = 8 waves (2m x 4n). Per-wave 128x64 out as 8 striped m-frags x 4 n-frags.
// LDS 128 KiB: double-buffered A[256][64] + B[256][64] bf16, per-row XOR-swizzled 16B slots.
// Stage order per tile: A-half0, B-half0, B-half1, A-half1 (1 per phase, for tile t+1).
// vmcnt(4) before P2-close barrier (confirms A-half1 of cur tile);
// vmcnt(2) before P4-close barrier (confirms A0/B0/B1 of next tile). Never 0 in main loop.
__global__ __launch_bounds__(512, 2) void k_gemm1_8ph(const unsigned short* __restrict__ hP,
                                                      const unsigned short* __restrict__ wP,
                                                      const float* __restrict__ bias,
                                                      float* __restrict__ C) {
  __shared__ unsigned short LA[2][16384];
  __shared__ unsigned short LB[2][16384];
  const int tid = threadIdx.x;
  const int w = tid >> 6, l = tid & 63;
  const int wm = w >> 2, wn = w & 3;
  // T1 XCD swizzle: 512 blocks, chunk 64 per XCD; within chunk n-fast (B reused in L2)
  const int bid = blockIdx.x;
  const int wid = (bid & 7) * 64 + (bid >> 3);
  const int m0 = (wid >> 2) * 256;
  const int n0 = (wid & 3) * 256;
  // staging addressing (linear LDS dest, pre-swizzled global k)
  const int srow = tid >> 3;                   // 0..63
  const int sk = ((tid & 7) ^ (srow & 7)) * 8; // element offset
  // fragment addressing
  const int fr = l & 15;
  const int fslot = l >> 4;

  f32x4 acc[8][4];
#pragma unroll
  for (int i = 0; i < 8; ++i)
#pragma unroll
    for (int j = 0; j < 4; ++j) acc[i][j] = (f32x4){0.f, 0.f, 0.f, 0.f};

  auto stage = [&](int buf, int which, int half, int tile) {
    const int s = tile >> 4, k0 = (tile & 15) << 6;
    const unsigned short* base;
    if (which == 0)
      base = hP + (size_t)((SA_BITS >> (2 * s)) & 3) * 33554432 + (size_t)(m0 + half * 128) * 1024;
    else
      base = wP + (size_t)((SB_BITS >> (2 * s)) & 3) * 1048576 + (size_t)(n0 + half * 128) * 1024;
    char* lds = (char*)(which ? LB[buf] : LA[buf]) + half * 16384;
#pragma unroll
    for (int i = 0; i < 2; ++i) {
      __builtin_amdgcn_global_load_lds(
          (const __attribute__((address_space(1))) void*)(base + (size_t)(srow + 64 * i) * 1024 + k0 + sk),
          (__attribute__((address_space(3))) void*)(lds + i * 8192 + tid * 16), 16, 0, 0);
    }
  };
  auto rdA = [&](int buf, int f, int ks) -> bf16x8 {
    const int row = (2 * f + wm) * 16 + fr;
    const int phys = (ks * 4 + fslot) ^ (row & 7);
    return *(const bf16x8*)((const char*)LA[buf] + row * 128 + phys * 16);
  };
  auto rdB = [&](int buf, int nf, int ks) -> bf16x8 {
    const int row = (4 * wn + nf) * 16 + fr;
    const int phys = (ks * 4 + fslot) ^ (row & 7);
    return *(const bf16x8*)((const char*)LB[buf] + row * 128 + phys * 16);
  };

  // prologue: stage tile 0 (A0,B0,B1,A1)
  stage(0, 0, 0, 0); __builtin_amdgcn_sched_barrier(0);
  stage(0, 1, 0, 0); __builtin_amdgcn_sched_barrier(0);
  stage(0, 1, 1, 0); __builtin_amdgcn_sched_barrier(0);
  stage(0, 0, 1, 0); __builtin_amdgcn_sched_barrier(0);
  VMCNT(2);
  BAR_MEM();

#define MFMA_QUAD(q, aq)                                                        \
  __builtin_amdgcn_s_setprio(1);                                                \
  _Pragma("unroll") for (int f2 = 0; f2 < 2; ++f2)                              \
    _Pragma("unroll") for (int nf = 0; nf < 4; ++nf)                            \
      _Pragma("unroll") for (int ks = 0; ks < 2; ++ks)                          \
        acc[2 * (q) + f2][nf] = __builtin_amdgcn_mfma_f32_16x16x32_bf16(        \
            aq[f2][ks], bfrag[nf][ks], acc[2 * (q) + f2][nf], 0, 0, 0);         \
  __builtin_amdgcn_s_setprio(0);

  for (int t = 0; t < 95; ++t) {
    const int cb = t & 1, nb = cb ^ 1;
    bf16x8 bfrag[4][2];
#pragma unroll
    for (int nf = 0; nf < 4; ++nf)
#pragma unroll
      for (int ks = 0; ks < 2; ++ks) bfrag[nf][ks] = rdB(cb, nf, ks);
    // P1
    {
      bf16x8 aq[2][2];
#pragma unroll
      for (int f2 = 0; f2 < 2; ++f2)
#pragma unroll
        for (int ks = 0; ks < 2; ++ks) aq[f2][ks] = rdA(cb, f2, ks);
      stage(nb, 0, 0, t + 1); __builtin_amdgcn_sched_barrier(0);
      __builtin_amdgcn_s_barrier();
      MFMA_QUAD(0, aq);
      BAR_MEM();
    }
    // P2
    {
      bf16x8 aq[2][2];
#pragma unroll
      for (int f2 = 0; f2 < 2; ++f2)
#pragma unroll
        for (int ks = 0; ks < 2; ++ks) aq[f2][ks] = rdA(cb, 2 + f2, ks);
      stage(nb, 1, 0, t + 1); __builtin_amdgcn_sched_barrier(0);
      __builtin_amdgcn_s_barrier();
      MFMA_QUAD(1, aq);
      VMCNT(4);   // A-half1 of cur tile landed (for P3/P4 reads after barrier)
      BAR_MEM();
    }
    // P3
    {
      bf16x8 aq[2][2];
#pragma unroll
      for (int f2 = 0; f2 < 2; ++f2)
#pragma unroll
        for (int ks = 0; ks < 2; ++ks) aq[f2][ks] = rdA(cb, 4 + f2, ks);
      stage(nb, 1, 1, t + 1); __builtin_amdgcn_sched_barrier(0);
      __builtin_amdgcn_s_barrier();
      MFMA_QUAD(2, aq);
      BAR_MEM();
    }
    // P4
    {
      bf16x8 aq[2][2];
#pragma unroll
      for (int f2 = 0; f2 < 2; ++f2)
#pragma unroll
        for (int ks = 0; ks < 2; ++ks) aq[f2][ks] = rdA(cb, 6 + f2, ks);
      stage(nb, 0, 1, t + 1); __builtin_amdgcn_sched_barrier(0);
      __builtin_amdgcn_s_barrier();
      MFMA_QUAD(3, aq);
      VMCNT(2);   // next tile's A0,B0,B1 landed; A1 stays in flight
      BAR_MEM();
    }
  }
  // epilogue tile t=95 (cb=1), no staging
  {
    const int cb = 1;
    bf16x8 bfrag[4][2];
#pragma unroll
    for (int nf = 0; nf < 4; ++nf)
#pragma unroll
      for (int ks = 0; ks < 2; ++ks) bfrag[nf][ks] = rdB(cb, nf, ks);
    {
      bf16x8 aq[2][2];
#pragma unroll
      for (int f2 = 0; f2 < 2; ++f2)
#pragma unroll
        for (int ks = 0; ks < 2; ++ks) aq[f2][ks] = rdA(cb, f2, ks);
      __builtin_amdgcn_s_barrier();
      MFMA_QUAD(0, aq);
    }
    {
      bf16x8 aq[2][2];
#pragma unroll
      for (int f2 = 0; f2 < 2; ++f2)
#pragma unroll
        for (int ks = 0; ks < 2; ++ks) aq[f2][ks] = rdA(cb, 2 + f2, ks);
      MFMA_QUAD(1, aq);
      VMCNT(0);   // A-half1 of last tile landed
      BAR_MEM();
    }
    {
      bf16x8 aq[2][2];
#pragma unroll
      for (int f2 = 0; f2 < 2; ++f2)
#pragma unroll
        for (int ks = 0; ks < 2; ++ks) aq[f2][ks] = rdA(cb, 4 + f2, ks);
      MFMA_QUAD(2, aq);
    }
    {
      bf16x8 aq[2][2];
#pragma unroll
      for (int f2 = 0; f2 < 2; ++f2)
#pragma unroll
        for (int ks = 0; ks < 2; ++ks) aq[f2][ks] = rdA(cb, 6 + f2, ks);
      MFMA_QUAD(3, aq);
    }
  }
#undef MFMA_QUAD
  // epilogue: C write
#pragma unroll
  for (int f = 0; f < 8; ++f) {
    const int row0 = m0 + (2 * f + wm) * 16 + (l >> 4) * 4;
#pragma unroll
    for (int nf = 0; nf < 4; ++nf) {
      const int col = n0 + (4 * wn + nf) * 16 + (l & 15);
      const float bb = bias[col];
#pragma unroll
      for (int r = 0; r < 4; ++r)
        C[(size_t)(row0 + r) * 1024 + col] = fmaxf(acc[f][nf][r] + bb, 0.f);
    }
  }
}

// ---------------- K1-fallback: fp32 vector GEMM (used when ws too small) ----------------
__global__ __launch_bounds__(256) void k_gemm1(const float* __restrict__ A,
                                               const float* __restrict__ Bm,
                                               const float* __restrict__ bias,
                                               float* __restrict__ C) {
  __shared__ float As[16][128];
  __shared__ float Bsh[16][128];
  const int tid = threadIdx.x;
  const int tx = tid & 15, ty = tid >> 4;
  const int n0 = blockIdx.x * 128, m0 = blockIdx.y * 128;
  const int ar = tid >> 1, ak = (tid & 1) * 8;
  const int bk = tid >> 4, bc = (tid & 15) * 8;
  float acc[2][2][4][4] = {};
  for (int k0 = 0; k0 < 1024; k0 += 16) {
    float4 a0 = *(const float4*)(A + (size_t)(m0 + ar) * 1024 + k0 + ak);
    float4 a1 = *(const float4*)(A + (size_t)(m0 + ar) * 1024 + k0 + ak + 4);
    float4 b0 = *(const float4*)(Bm + (size_t)(k0 + bk) * 1024 + n0 + bc);
    float4 b1v = *(const float4*)(Bm + (size_t)(k0 + bk) * 1024 + n0 + bc + 4);
    __syncthreads();
    As[ak + 0][ar] = a0.x; As[ak + 1][ar] = a0.y; As[ak + 2][ar] = a0.z; As[ak + 3][ar] = a0.w;
    As[ak + 4][ar] = a1.x; As[ak + 5][ar] = a1.y; As[ak + 6][ar] = a1.z; As[ak + 7][ar] = a1.w;
    *(float4*)&Bsh[bk][bc] = b0;
    *(float4*)&Bsh[bk][bc + 4] = b1v;
    __syncthreads();
#pragma unroll
    for (int kk = 0; kk < 16; ++kk) {
      float4 aA = *(const float4*)&As[kk][ty * 4];
      float4 aB = *(const float4*)&As[kk][64 + ty * 4];
      float4 bA = *(const float4*)&Bsh[kk][tx * 4];
      float4 bB = *(const float4*)&Bsh[kk][64 + tx * 4];
      float av[2][4] = {{aA.x, aA.y, aA.z, aA.w}, {aB.x, aB.y, aB.z, aB.w}};
      float bv[2][4] = {{bA.x, bA.y, bA.z, bA.w}, {bB.x, bB.y, bB.z, bB.w}};
#pragma unroll
      for (int ri = 0; ri < 2; ++ri)
#pragma unroll
        for (int i = 0; i < 4; ++i)
#pragma unroll
          for (int rj = 0; rj < 2; ++rj)
#pragma unroll
            for (int j = 0; j < 4; ++j)
              acc[ri][rj][i][j] = fmaf(av[ri][i], bv[rj][j], acc[ri][rj][i][j]);
    }
  }
#pragma unroll
  for (int ri = 0; ri < 2; ++ri)
#pragma unroll
    for (int i = 0; i < 4; ++i) {
      int row = m0 + ri * 64 + ty * 4 + i;
#pragma unroll
      for (int rj = 0; rj < 2; ++rj) {
        int col = n0 + rj * 64 + tx * 4;
        float4 o;
        o.x = fmaxf(acc[ri][rj][i][0] + bias[col + 0], 0.f);
        o.y = fmaxf(acc[ri][rj][i][1] + bias[col + 1], 0.f);
        o.z = fmaxf(acc[ri][rj][i][2] + bias[col + 2], 0.f);
        o.w = fmaxf(acc[ri][rj][i][3] + bias[col + 3], 0.f);
        *(float4*)(C + (size_t)row * 1024 + col) = o;
      }
    }
}

// ---------------- K2: ner = C1 @ W2T^T + b2; softmax; argmax ----------------
__global__ __launch_bounds__(256) void k_ner(const float* __restrict__ C1,
                                             const float* __restrict__ W2T,
                                             const float* __restrict__ b2,
                                             float* __restrict__ ner_out,
                                             float* __restrict__ softm,
                                             int* __restrict__ amax) {
  const int wave = threadIdx.x >> 6, lane = threadIdx.x & 63;
  const int row0 = blockIdx.x * 16 + wave * 4;
  float acc[4][17];
#pragma unroll
  for (int r = 0; r < 4; ++r)
#pragma unroll
    for (int c = 0; c < 17; ++c) acc[r][c] = 0.f;
  for (int kb = 0; kb < 16; ++kb) {
    int k = kb * 64 + lane;
    float w2l[17];
#pragma unroll
    for (int c = 0; c < 17; ++c) w2l[c] = W2T[c * 1024 + k];
#pragma unroll
    for (int r = 0; r < 4; ++r) {
      float v = C1[(size_t)(row0 + r) * 1024 + k];
#pragma unroll
      for (int c = 0; c < 17; ++c) acc[r][c] = fmaf(v, w2l[c], acc[r][c]);
    }
  }
#pragma unroll
  for (int off = 32; off > 0; off >>= 1) {
#pragma unroll
    for (int r = 0; r < 4; ++r)
#pragma unroll
      for (int c = 0; c < 17; ++c) acc[r][c] += __shfl_xor(acc[r][c], off);
  }
  if (lane < 4) {
    const int row = row0 + lane;
    float v[17];
#pragma unroll
    for (int c = 0; c < 17; ++c) v[c] = acc[lane][c] + b2[c];
    float mx = v[0]; int am = 0;
#pragma unroll
    for (int c = 1; c < 17; ++c) { if (v[c] > mx) { mx = v[c]; am = c; } }
    float s = 0.f, e[17];
#pragma unroll
    for (int c = 0; c < 17; ++c) { e[c] = __expf(v[c] - mx); s += e[c]; }
    const float inv = 1.f / s;
    float* sm = softm + (size_t)row * 17;
#pragma unroll
    for (int c = 0; c < 17; ++c) sm[c] = e[c] * inv;
    amax[row] = am;
    const int b = row >> 10, sidx = row & 1023;
    if (sidx >= 1) {
      float* no = ner_out + ((size_t)b * SMM + sidx - 1) * 17;
#pragma unroll
      for (int c = 0; c < 17; ++c) no[c] = v[c];
    }
  }
}

// ---------------- K3: span logic + entity selection + pos_pairs ----------------
__global__ __launch_bounds__(64) void k_spans(const int* __restrict__ amax,
                                              int* __restrict__ meta,
                                              float* __restrict__ pp_out) {
  const int b = blockIdx.x, lane = threadIdx.x;
  __shared__ int nextE[4][1023];
  __shared__ int slist[4][10], blj[4][10], ble[4][10];
  __shared__ int ns[4], nb[4];
  __shared__ int posq[10];
  const int* am = amax + b * 1024 + 1;
  if (lane < 4) {
    const int t = lane;
    int cur = SMM;
    for (int j = SMM - 1; j >= 0; --j) {
      nextE[t][j] = cur;
      if (am[j] == 3 + 4 * t) cur = j;
    }
    int end = -1, cs = 0, cb = 0;
    for (int j = 0; j < SMM; ++j) {
      int a = am[j];
      if (a == 4 + 4 * t && cs < 10) slist[t][cs++] = j;
      if (a == 1 + 4 * t && j > end) {
        end = nextE[t][j];
        if (cb < 10) { blj[t][cb] = j; ble[t][cb] = end; cb++; }
      }
    }
    ns[t] = cs; nb[t] = cb;
  }
  __syncthreads();
  if (lane == 0) {
    int q = 0;
    for (int t = 0; t < 4 && q < 10; ++t) {
      for (int s = 0; s < ns[t] && q < 10; ++s) {
        int j = slist[t][s];
        int* m = meta + (b * 10 + q) * 4;
        m[0] = j; m[1] = j + 1; m[2] = 1; m[3] = 1;
        posq[q] = j + 1; ++q;
      }
      for (int s = 0; s < nb[t] && q < 10; ++s) {
        int j = blj[t][s], e = ble[t][s];
        int* m = meta + (b * 10 + q) * 4;
        m[0] = j; m[1] = e; m[2] = e - j; m[3] = 1;
        posq[q] = e + 1; ++q;
      }
    }
    for (; q < 10; ++q) {
      int* m = meta + (b * 10 + q) * 4;
      m[0] = 0; m[1] = 0; m[2] = 1; m[3] = 0;
      posq[q] = -1;
    }
  }
  __syncthreads();
  for (int pr = lane; pr < NPAIR; pr += 64) {
    int i = pr / 9, jj = pr % 9;
    int j = jj + (jj >= i ? 1 : 0);
    pp_out[(size_t)(b * NPAIR + pr) * 2 + 0] = (float)posq[i];
    pp_out[(size_t)(b * NPAIR + pr) * 2 + 1] = (float)posq[j];
  }
}

// ---------------- K4: ents = segment means ----------------
__global__ __launch_bounds__(256) void k_ents(const float* __restrict__ h,
                                              const float* __restrict__ softm,
                                              const int* __restrict__ meta,
                                              float* __restrict__ ents) {
  const int bq = blockIdx.x;
  const int b = bq / 10;
  const int* m = meta + bq * 4;
  const int j0 = m[0], e = m[1], len = m[2], vs = m[3];
  float acc[5] = {0.f, 0.f, 0.f, 0.f, 0.f};
  for (int row = j0; row < e; ++row) {
    const int s = row + 1;
    const float* hr = h + (size_t)(b * 1024 + s) * 1024;
    const float* sr = softm + (size_t)(b * 1024 + s) * 17;
#pragma unroll
    for (int i = 0; i < 5; ++i) {
      int d = threadIdx.x + i * 256;
      if (d < DXX) acc[i] += (d < 1024 ? hr[d] : sr[d - 1024]);
    }
  }
  const float inv = vs ? (1.0f / (float)len) : 0.0f;
#pragma unroll
  for (int i = 0; i < 5; ++i) {
    int d = threadIdx.x + i * 256;
    if (d < DXX) ents[(size_t)bq * DXX + d] = acc[i] * inv;
  }
}

// ---------------- K5a: fused head/tail layer-1 ----------------
__global__ __launch_bounds__(512) void k_mlp_l1(const float* __restrict__ ents,
                                                const float* __restrict__ Wh1, const float* __restrict__ bh1,
                                                const float* __restrict__ Wt1, const float* __restrict__ bt1,
                                                float* __restrict__ H1, float* __restrict__ T1) {
  __shared__ float e[2][DXX];
  const int r0 = blockIdx.x * 2;
  const int chain = blockIdx.y;
  const float* W = chain ? Wt1 : Wh1;
  const float* bi = chain ? bt1 : bh1;
  float* out = chain ? T1 : H1;
  for (int idx = threadIdx.x; idx < 2 * DXX; idx += 512) {
    int row = idx >= DXX;
    int col = row ? idx - DXX : idx;
    e[row][col] = ents[(size_t)(r0 + row) * DXX + col];
  }
  __syncthreads();
  const int n = threadIdx.x;
  float a0 = 0.f, a1 = 0.f;
#pragma unroll 4
  for (int k = 0; k < DXX; ++k) {
    float w = W[(size_t)k * 512 + n];
    a0 = fmaf(e[0][k], w, a0);
    a1 = fmaf(e[1][k], w, a1);
  }
  const float bv = bi[n];
  out[(size_t)r0 * 512 + n] = fmaxf(a0 + bv, 0.f);
  out[(size_t)(r0 + 1) * 512 + n] = fmaxf(a1 + bv, 0.f);
}

// ---------------- K5b: fused head/tail layer-2 ----------------
__global__ __launch_bounds__(512) void k_mlp_l2(const float* __restrict__ H1, const float* __restrict__ T1,
                                                const float* __restrict__ Wh2, const float* __restrict__ bh2,
                                                const float* __restrict__ Wt2, const float* __restrict__ bt2,
                                                float* __restrict__ headp, float* __restrict__ tailp) {
  __shared__ float e[2][512];
  const int r0 = blockIdx.x * 2;
  const int chain = blockIdx.y;
  const float* in = chain ? T1 : H1;
  const float* W = chain ? Wt2 : Wh2;
  const float* bi = chain ? bt2 : bh2;
  float* out = chain ? tailp : headp;
  for (int idx = threadIdx.x; idx < 1024; idx += 512)
    e[idx >> 9][idx & 511] = in[(size_t)r0 * 512 + idx];
  __syncthreads();
  const int n = threadIdx.x;
  float a0 = 0.f, a1 = 0.f;
#pragma unroll 4
  for (int k = 0; k < 512; ++k) {
    float w = W[(size_t)k * 512 + n];
    a0 = fmaf(e[0][k], w, a0);
    a1 = fmaf(e[1][k], w, a1);
  }
  const float bv = bi[n];
  out[(size_t)r0 * 512 + n] = a0 + bv;
  out[(size_t)(r0 + 1) * 512 + n] = a1 + bv;
}

// ---------------- K5c: bilinear u[o] = headp @ Wbil[o], 64x64 tiled reg-blocked ----------------
__global__ __launch_bounds__(256) void k_bil(const float* __restrict__ headp,
                                             const float* __restrict__ Wbil,
                                             float* __restrict__ u) {
  __shared__ float As[16][64];  // [k][m]
  __shared__ float Bs[16][64];  // [k][n]
  const int o = blockIdx.z;
  const int m0 = blockIdx.y * 64, n0 = blockIdx.x * 64;
  const int tx = threadIdx.x & 15, ty = threadIdx.x >> 4;
  const float* Wo = Wbil + (size_t)o * 262144;
  float acc[4][4] = {};
  for (int k0 = 0; k0 < 512; k0 += 16) {
    float4 av4 = *(const float4*)(headp + (size_t)(m0 + (threadIdx.x >> 2)) * 512 + k0 + (threadIdx.x & 3) * 4);
    float4 bv4 = *(const float4*)(Wo + (size_t)(k0 + (threadIdx.x >> 4)) * 512 + n0 + (threadIdx.x & 15) * 4);
    __syncthreads();
    As[(threadIdx.x & 3) * 4 + 0][threadIdx.x >> 2] = av4.x;
    As[(threadIdx.x & 3) * 4 + 1][threadIdx.x >> 2] = av4.y;
    As[(threadIdx.x & 3) * 4 + 2][threadIdx.x >> 2] = av4.z;
    As[(threadIdx.x & 3) * 4 + 3][threadIdx.x >> 2] = av4.w;
    *(float4*)&Bs[threadIdx.x >> 4][(threadIdx.x & 15) * 4] = bv4;
    __syncthreads();
#pragma unroll
    for (int kk = 0; kk < 16; ++kk) {
      float4 a = *(const float4*)&As[kk][ty * 4];
      float4 b = *(const float4*)&Bs[kk][tx * 4];
      float av[4] = {a.x, a.y, a.z, a.w};
      float bv[4] = {b.x, b.y, b.z, b.w};
#pragma unroll
      for (int i = 0; i < 4; ++i)
#pragma unroll
        for (int j = 0; j < 4; ++j)
          acc[i][j] = fmaf(av[i], bv[j], acc[i][j]);
    }
  }
#pragma unroll
  for (int i = 0; i < 4; ++i) {
    float4 ov = {acc[i][0], acc[i][1], acc[i][2], acc[i][3]};
    *(float4*)(u + ((size_t)o * 320 + m0 + ty * 4 + i) * 512 + n0 + tx * 4) = ov;
  }
}

// ---------------- K6: lh/lt = head/tail @ Wlin parts ----------------
__global__ __launch_bounds__(256) void k_lin(const float* __restrict__ headp,
                                             const float* __restrict__ tailp,
                                             const float* __restrict__ Wlin,
                                             float* __restrict__ lh,
                                             float* __restrict__ lt) {
  __shared__ float redH[4][16], redT[4][16];
  const int r = blockIdx.x;
  const int wv = threadIdx.x >> 6, lane = threadIdx.x & 63;
  const float* hr = headp + (size_t)r * 512;
  const float* tr = tailp + (size_t)r * 512;
  float a[16], bacc[16];
#pragma unroll
  for (int o = 0; o < 16; ++o) { a[o] = 0.f; bacc[o] = 0.f; }
#pragma unroll
  for (int kk = 0; kk < 2; ++kk) {
    const int k = wv * 128 + kk * 64 + lane;
    const float hv = hr[k], tv = tr[k];
#pragma unroll
    for (int o = 0; o < 16; ++o) {
      a[o] = fmaf(hv, Wlin[o * 1024 + k], a[o]);
      bacc[o] = fmaf(tv, Wlin[o * 1024 + 512 + k], bacc[o]);
    }
  }
#pragma unroll
  for (int off = 32; off > 0; off >>= 1) {
#pragma unroll
    for (int o = 0; o < 16; ++o) {
      a[o] += __shfl_xor(a[o], off);
      bacc[o] += __shfl_xor(bacc[o], off);
    }
  }
  if (lane == 0) {
#pragma unroll
    for (int o = 0; o < 16; ++o) { redH[wv][o] = a[o]; redT[wv][o] = bacc[o]; }
  }
  __syncthreads();
  if (threadIdx.x < 16) {
    const int o = threadIdx.x;
    float s = 0.f, t = 0.f;
#pragma unroll
    for (int w2 = 0; w2 < 4; ++w2) { s += redH[w2][o]; t += redT[w2][o]; }
    lh[r * 16 + o] = s;
    lt[r * 16 + o] = t;
  }
}

// ---------------- K7: re ----------------
__global__ __launch_bounds__(256) void k_re(const float* __restrict__ u,
                                            const float* __restrict__ tailp,
                                            const float* __restrict__ lh,
                                            const float* __restrict__ lt,
                                            const float* __restrict__ bbil,
                                            float* __restrict__ re_out) {
  const int bp = blockIdx.x;
  const int b = bp / NPAIR, pr = bp % NPAIR;
  const int i = pr / 9, jj = pr % 9;
  const int j = jj + (jj >= i ? 1 : 0);
  const int wave = threadIdx.x >> 6, lane = threadIdx.x & 63;
  const float* tj = tailp + (size_t)(b * 10 + j) * 512;
#pragma unroll
  for (int oo = 0; oo < 4; ++oo) {
    const int o = wave + oo * 4;
    const float* uo = u + ((size_t)o * 320 + b * 10 + i) * 512;
    float acc = 0.f;
    for (int k = lane; k < 512; k += 64) acc = fmaf(uo[k], tj[k], acc);
#pragma unroll
    for (int off = 32; off > 0; off >>= 1) acc += __shfl_xor(acc, off);
    if (lane == 0)
      re_out[(size_t)bp * 16 + o] = acc + bbil[o] + lh[(b * 10 + i) * 16 + o] + lt[(b * 10 + j) * 16 + o];
  }
}

// ---------------- launch ----------------
extern "C" void kernel_launch(void* const* d_in, const int* in_sizes, int n_in,
                              void* d_out, int out_size, void* d_ws, size_t ws_size,
                              hipStream_t stream) {
  const float* h    = (const float*)d_in[0];
  const float* W1   = (const float*)d_in[1];
  const float* b1   = (const float*)d_in[2];
  const float* W2   = (const float*)d_in[3];
  const float* b2   = (const float*)d_in[4];
  const float* Wh1  = (const float*)d_in[5];
  const float* bh1  = (const float*)d_in[6];
  const float* Wh2  = (const float*)d_in[7];
  const float* bh2  = (const float*)d_in[8];
  const float* Wt1  = (const float*)d_in[9];
  const float* bt1  = (const float*)d_in[10];
  const float* Wt2  = (const float*)d_in[11];
  const float* bt2  = (const float*)d_in[12];
  const float* Wbil = (const float*)d_in[13];
  const float* bbil = (const float*)d_in[14];
  const float* Wlin = (const float*)d_in[15];

  float* out = (float*)d_out;
  float* ner_out = out;
  float* pp_out  = out + 556512;
  float* re_out  = out + 562272;

  char* ws = (char*)d_ws;
  float* C1    = (float*)(ws + 0);            // 134217728
  float* softm = (float*)(ws + 134217728);    // 2228224
  int*   amax  = (int*)  (ws + 136445952);    // 131072
  int*   meta  = (int*)  (ws + 136577024);    // 5120
  float* ents  = (float*)(ws + 136582144);    // 1332480
  float* H1    = (float*)(ws + 137914624);    // 655360
  float* T1    = (float*)(ws + 138569984);    // 655360
  float* headp = (float*)(ws + 139225344);    // 655360
  float* tailp = (float*)(ws + 139880704);    // 655360
  float* u     = (float*)(ws + 140536064);    // 10485760
  float* lh    = (float*)(ws + 151021824);    // 20480
  float* lt    = (float*)(ws + 151042304);    // 20480
  float* W2T   = (float*)(ws + 151062784);    // 69632
  unsigned short* wP = (unsigned short*)(ws + 151132416);   // 6291456
  unsigned short* hP = (unsigned short*)(ws + 157423872);   // 201326592
  const size_t NEED_FULL = 358750464;
  const size_t NEED_W2T  = 151132416;

  const bool full = ws_size >= NEED_FULL;
  const bool haveW2T = ws_size >= NEED_W2T;

  if (full) {
    k_split_h<<<2048, 256, 0, stream>>>((const float4*)h, (ushort4*)hP,
                                        (ushort4*)(hP + 33554432), (ushort4*)(hP + 67108864));
    k_split_w<<<dim3(32, 32), 256, 0, stream>>>(W1, wP);
    k_gemm1_8ph<<<512, 512, 0, stream>>>(hP, wP, b1, C1);
  } else {
    k_gemm1<<<dim3(8, 256), 256, 0, stream>>>(h, W1, b1, C1);
  }
  if (haveW2T) {
    k_w2t<<<dim3(17, 4), 256, 0, stream>>>(W2, W2T);
    k_ner<<<2048, 256, 0, stream>>>(C1, W2T, b2, ner_out, softm, amax);
  } else {
    k_w2t<<<dim3(17, 4), 256, 0, stream>>>(W2, (float*)(ws + 140536064));
    k_ner<<<2048, 256, 0, stream>>>(C1, (float*)(ws + 140536064), b2, ner_out, softm, amax);
  }
  k_spans<<<32, 64, 0, stream>>>(amax, meta, pp_out);
  k_ents<<<320, 256, 0, stream>>>(h, softm, meta, ents);
  k_mlp_l1<<<dim3(160, 2), 512, 0, stream>>>(ents, Wh1, bh1, Wt1, bt1, H1, T1);
  k_mlp_l2<<<dim3(160, 2), 512, 0, stream>>>(H1, T1, Wh2, bh2, Wt2, bt2, headp, tailp);
  k_bil<<<dim3(8, 5, 16), 256, 0, stream>>>(headp, Wbil, u);
  k_lin<<<320, 256, 0, stream>>>(headp, tailp, Wlin, lh, lt);
  k_re<<<2880, 256, 0, stream>>>(u, tailp, lh, lt, bbil, re_out);
}

// Round 5
// 1249.522 us; speedup vs baseline: 1.4367x; 1.0016x over previous
//
#include <hip/hip_runtime.h>
#include <hip/hip_bf16.h>

// ---------------- constants ----------------
#define BB   32
#define SS   1024
#define DD   1024
#define SMM  1023
#define NER  17
#define HH   512
#define DXX  1041
#define PP   10
#define NPAIR 90

typedef __bf16 bf16x8 __attribute__((ext_vector_type(8)));
typedef float f32x4 __attribute__((ext_vector_type(4)));

#define VMCNT(n) asm volatile("s_waitcnt vmcnt(" #n ")" ::: "memory")
#define BAR_MEM() asm volatile("s_barrier" ::: "memory")

// segment plane selectors: s=0..5 -> (a,b) = (2,0)(1,1)(0,2)(1,0)(0,1)(0,0), small terms first
#define SA_BITS (2u | (1u << 2) | (0u << 4) | (1u << 6) | (0u << 8) | (0u << 10))
#define SB_BITS (0u | (1u << 2) | (2u << 4) | (0u << 6) | (1u << 8) | (0u << 10))

// ---------------- split helpers ----------------
__device__ inline void split3(float x, unsigned short& s0, unsigned short& s1, unsigned short& s2) {
  __hip_bfloat16 h0 = __float2bfloat16(x);
  float f0 = __bfloat162float(h0);
  float r1 = x - f0;
  __hip_bfloat16 h1 = __float2bfloat16(r1);
  float f1 = __bfloat162float(h1);
  float r2 = r1 - f1;
  __hip_bfloat16 h2 = __float2bfloat16(r2);
  s0 = *reinterpret_cast<unsigned short*>(&h0);
  s1 = *reinterpret_cast<unsigned short*>(&h1);
  s2 = *reinterpret_cast<unsigned short*>(&h2);
}

// ---------------- K0a: split h into 3 bf16 planes ----------------
__global__ __launch_bounds__(256) void k_split_h(const float4* __restrict__ h4,
                                                 ushort4* __restrict__ p0,
                                                 ushort4* __restrict__ p1,
                                                 ushort4* __restrict__ p2) {
  const int idx = blockIdx.x * 256 + threadIdx.x;
  for (int i = idx; i < 8388608; i += 524288) {
    float4 v = h4[i];
    ushort4 a, b, c;
    split3(v.x, a.x, b.x, c.x);
    split3(v.y, a.y, b.y, c.y);
    split3(v.z, a.z, b.z, c.z);
    split3(v.w, a.w, b.w, c.w);
    p0[i] = a; p1[i] = b; p2[i] = c;
  }
}

// ---------------- K0b: split + transpose W1 -> 3 bf16 planes of W1^T [n][k] ----------------
__global__ __launch_bounds__(256) void k_split_w(const float* __restrict__ W,
                                                 unsigned short* __restrict__ wP) {
  __shared__ float t[32][33];
  const int bk = blockIdx.x * 32, bn = blockIdx.y * 32;
  const int tr = threadIdx.x >> 5, tc = threadIdx.x & 31;
#pragma unroll
  for (int i = 0; i < 4; ++i)
    t[tr + i * 8][tc] = W[(size_t)(bk + tr + i * 8) * 1024 + bn + tc];
  __syncthreads();
#pragma unroll
  for (int i = 0; i < 4; ++i) {
    const int n = bn + tr + i * 8, k = bk + tc;
    unsigned short s0, s1, s2;
    split3(t[tc][tr + i * 8], s0, s1, s2);
    wP[(size_t)n * 1024 + k] = s0;
    wP[1048576 + (size_t)n * 1024 + k] = s1;
    wP[2097152 + (size_t)n * 1024 + k] = s2;
  }
}

// ---------------- K0c: transpose W2 -> W2T[17][1024] ----------------
__global__ void k_w2t(const float* __restrict__ W2, float* __restrict__ W2T) {
  const int c = blockIdx.x, k = blockIdx.y * 256 + threadIdx.x;
  W2T[c * 1024 + k] = W2[k * 17 + c];
}

// ---------------- K1: 256x256 8-phase MFMA GEMM, bf16x3 6-product, K'=6144 ----------------
__global__ __launch_bounds__(512, 2) void k_gemm1_8ph(const unsigned short* __restrict__ hP,
                                                      const unsigned short* __restrict__ wP,
                                                      const float* __restrict__ bias,
                                                      float* __restrict__ C) {
  __shared__ unsigned short LA[2][16384];
  __shared__ unsigned short LB[2][16384];
  const int tid = threadIdx.x;
  const int w = tid >> 6, l = tid & 63;
  const int wm = w >> 2, wn = w & 3;
  const int bid = blockIdx.x;
  const int wid = (bid & 7) * 64 + (bid >> 3);
  const int m0 = (wid >> 2) * 256;
  const int n0 = (wid & 3) * 256;
  const int srow = tid >> 3;
  const int sk = ((tid & 7) ^ (srow & 7)) * 8;
  const int fr = l & 15;
  const int fslot = l >> 4;

  f32x4 acc[8][4];
#pragma unroll
  for (int i = 0; i < 8; ++i)
#pragma unroll
    for (int j = 0; j < 4; ++j) acc[i][j] = (f32x4){0.f, 0.f, 0.f, 0.f};

  auto stage = [&](int buf, int which, int half, int tile) {
    const int s = tile >> 4, k0 = (tile & 15) << 6;
    const unsigned short* base;
    if (which == 0)
      base = hP + (size_t)((SA_BITS >> (2 * s)) & 3) * 33554432 + (size_t)(m0 + half * 128) * 1024;
    else
      base = wP + (size_t)((SB_BITS >> (2 * s)) & 3) * 1048576 + (size_t)(n0 + half * 128) * 1024;
    char* lds = (char*)(which ? LB[buf] : LA[buf]) + half * 16384;
#pragma unroll
    for (int i = 0; i < 2; ++i) {
      __builtin_amdgcn_global_load_lds(
          (const __attribute__((address_space(1))) void*)(base + (size_t)(srow + 64 * i) * 1024 + k0 + sk),
          (__attribute__((address_space(3))) void*)(lds + i * 8192 + tid * 16), 16, 0, 0);
    }
  };
  auto rdA = [&](int buf, int f, int ks) -> bf16x8 {
    const int row = (2 * f + wm) * 16 + fr;
    const int phys = (ks * 4 + fslot) ^ (row & 7);
    return *(const bf16x8*)((const char*)LA[buf] + row * 128 + phys * 16);
  };
  auto rdB = [&](int buf, int nf, int ks) -> bf16x8 {
    const int row = (4 * wn + nf) * 16 + fr;
    const int phys = (ks * 4 + fslot) ^ (row & 7);
    return *(const bf16x8*)((const char*)LB[buf] + row * 128 + phys * 16);
  };

  stage(0, 0, 0, 0); __builtin_amdgcn_sched_barrier(0);
  stage(0, 1, 0, 0); __builtin_amdgcn_sched_barrier(0);
  stage(0, 1, 1, 0); __builtin_amdgcn_sched_barrier(0);
  stage(0, 0, 1, 0); __builtin_amdgcn_sched_barrier(0);
  VMCNT(2);
  BAR_MEM();

#define MFMA_QUAD(q, aq)                                                        \
  __builtin_amdgcn_s_setprio(1);                                                \
  _Pragma("unroll") for (int f2 = 0; f2 < 2; ++f2)                              \
    _Pragma("unroll") for (int nf = 0; nf < 4; ++nf)                            \
      _Pragma("unroll") for (int ks = 0; ks < 2; ++ks)                          \
        acc[2 * (q) + f2][nf] = __builtin_amdgcn_mfma_f32_16x16x32_bf16(        \
            aq[f2][ks], bfrag[nf][ks], acc[2 * (q) + f2][nf], 0, 0, 0);         \
  __builtin_amdgcn_s_setprio(0);

  for (int t = 0; t < 95; ++t) {
    const int cb = t & 1, nb = cb ^ 1;
    bf16x8 bfrag[4][2];
#pragma unroll
    for (int nf = 0; nf < 4; ++nf)
#pragma unroll
      for (int ks = 0; ks < 2; ++ks) bfrag[nf][ks] = rdB(cb, nf, ks);
    {
      bf16x8 aq[2][2];
#pragma unroll
      for (int f2 = 0; f2 < 2; ++f2)
#pragma unroll
        for (int ks = 0; ks < 2; ++ks) aq[f2][ks] = rdA(cb, f2, ks);
      stage(nb, 0, 0, t + 1); __builtin_amdgcn_sched_barrier(0);
      __builtin_amdgcn_s_barrier();
      MFMA_QUAD(0, aq);
      BAR_MEM();
    }
    {
      bf16x8 aq[2][2];
#pragma unroll
      for (int f2 = 0; f2 < 2; ++f2)
#pragma unroll
        for (int ks = 0; ks < 2; ++ks) aq[f2][ks] = rdA(cb, 2 + f2, ks);
      stage(nb, 1, 0, t + 1); __builtin_amdgcn_sched_barrier(0);
      __builtin_amdgcn_s_barrier();
      MFMA_QUAD(1, aq);
      VMCNT(4);
      BAR_MEM();
    }
    {
      bf16x8 aq[2][2];
#pragma unroll
      for (int f2 = 0; f2 < 2; ++f2)
#pragma unroll
        for (int ks = 0; ks < 2; ++ks) aq[f2][ks] = rdA(cb, 4 + f2, ks);
      stage(nb, 1, 1, t + 1); __builtin_amdgcn_sched_barrier(0);
      __builtin_amdgcn_s_barrier();
      MFMA_QUAD(2, aq);
      BAR_MEM();
    }
    {
      bf16x8 aq[2][2];
#pragma unroll
      for (int f2 = 0; f2 < 2; ++f2)
#pragma unroll
        for (int ks = 0; ks < 2; ++ks) aq[f2][ks] = rdA(cb, 6 + f2, ks);
      stage(nb, 0, 1, t + 1); __builtin_amdgcn_sched_barrier(0);
      __builtin_amdgcn_s_barrier();
      MFMA_QUAD(3, aq);
      VMCNT(2);
      BAR_MEM();
    }
  }
  {
    const int cb = 1;
    bf16x8 bfrag[4][2];
#pragma unroll
    for (int nf = 0; nf < 4; ++nf)
#pragma unroll
      for (int ks = 0; ks < 2; ++ks) bfrag[nf][ks] = rdB(cb, nf, ks);
    {
      bf16x8 aq[2][2];
#pragma unroll
      for (int f2 = 0; f2 < 2; ++f2)
#pragma unroll
        for (int ks = 0; ks < 2; ++ks) aq[f2][ks] = rdA(cb, f2, ks);
      __builtin_amdgcn_s_barrier();
      MFMA_QUAD(0, aq);
    }
    {
      bf16x8 aq[2][2];
#pragma unroll
      for (int f2 = 0; f2 < 2; ++f2)
#pragma unroll
        for (int ks = 0; ks < 2; ++ks) aq[f2][ks] = rdA(cb, 2 + f2, ks);
      MFMA_QUAD(1, aq);
      VMCNT(0);
      BAR_MEM();
    }
    {
      bf16x8 aq[2][2];
#pragma unroll
      for (int f2 = 0; f2 < 2; ++f2)
#pragma unroll
        for (int ks = 0; ks < 2; ++ks) aq[f2][ks] = rdA(cb, 4 + f2, ks);
      MFMA_QUAD(2, aq);
    }
    {
      bf16x8 aq[2][2];
#pragma unroll
      for (int f2 = 0; f2 < 2; ++f2)
#pragma unroll
        for (int ks = 0; ks < 2; ++ks) aq[f2][ks] = rdA(cb, 6 + f2, ks);
      MFMA_QUAD(3, aq);
    }
  }
#undef MFMA_QUAD
#pragma unroll
  for (int f = 0; f < 8; ++f) {
    const int row0 = m0 + (2 * f + wm) * 16 + (l >> 4) * 4;
#pragma unroll
    for (int nf = 0; nf < 4; ++nf) {
      const int col = n0 + (4 * wn + nf) * 16 + (l & 15);
      const float bb = bias[col];
#pragma unroll
      for (int r = 0; r < 4; ++r)
        C[(size_t)(row0 + r) * 1024 + col] = fmaxf(acc[f][nf][r] + bb, 0.f);
    }
  }
}

// ---------------- K1-fallback: fp32 vector GEMM (used when ws too small) ----------------
__global__ __launch_bounds__(256) void k_gemm1(const float* __restrict__ A,
                                               const float* __restrict__ Bm,
                                               const float* __restrict__ bias,
                                               float* __restrict__ C) {
  __shared__ float As[16][128];
  __shared__ float Bsh[16][128];
  const int tid = threadIdx.x;
  const int tx = tid & 15, ty = tid >> 4;
  const int n0 = blockIdx.x * 128, m0 = blockIdx.y * 128;
  const int ar = tid >> 1, ak = (tid & 1) * 8;
  const int bk = tid >> 4, bc = (tid & 15) * 8;
  float acc[2][2][4][4] = {};
  for (int k0 = 0; k0 < 1024; k0 += 16) {
    float4 a0 = *(const float4*)(A + (size_t)(m0 + ar) * 1024 + k0 + ak);
    float4 a1 = *(const float4*)(A + (size_t)(m0 + ar) * 1024 + k0 + ak + 4);
    float4 b0 = *(const float4*)(Bm + (size_t)(k0 + bk) * 1024 + n0 + bc);
    float4 b1v = *(const float4*)(Bm + (size_t)(k0 + bk) * 1024 + n0 + bc + 4);
    __syncthreads();
    As[ak + 0][ar] = a0.x; As[ak + 1][ar] = a0.y; As[ak + 2][ar] = a0.z; As[ak + 3][ar] = a0.w;
    As[ak + 4][ar] = a1.x; As[ak + 5][ar] = a1.y; As[ak + 6][ar] = a1.z; As[ak + 7][ar] = a1.w;
    *(float4*)&Bsh[bk][bc] = b0;
    *(float4*)&Bsh[bk][bc + 4] = b1v;
    __syncthreads();
#pragma unroll
    for (int kk = 0; kk < 16; ++kk) {
      float4 aA = *(const float4*)&As[kk][ty * 4];
      float4 aB = *(const float4*)&As[kk][64 + ty * 4];
      float4 bA = *(const float4*)&Bsh[kk][tx * 4];
      float4 bB = *(const float4*)&Bsh[kk][64 + tx * 4];
      float av[2][4] = {{aA.x, aA.y, aA.z, aA.w}, {aB.x, aB.y, aB.z, aB.w}};
      float bv[2][4] = {{bA.x, bA.y, bA.z, bA.w}, {bB.x, bB.y, bB.z, bB.w}};
#pragma unroll
      for (int ri = 0; ri < 2; ++ri)
#pragma unroll
        for (int i = 0; i < 4; ++i)
#pragma unroll
          for (int rj = 0; rj < 2; ++rj)
#pragma unroll
            for (int j = 0; j < 4; ++j)
              acc[ri][rj][i][j] = fmaf(av[ri][i], bv[rj][j], acc[ri][rj][i][j]);
    }
  }
#pragma unroll
  for (int ri = 0; ri < 2; ++ri)
#pragma unroll
    for (int i = 0; i < 4; ++i) {
      int row = m0 + ri * 64 + ty * 4 + i;
#pragma unroll
      for (int rj = 0; rj < 2; ++rj) {
        int col = n0 + rj * 64 + tx * 4;
        float4 o;
        o.x = fmaxf(acc[ri][rj][i][0] + bias[col + 0], 0.f);
        o.y = fmaxf(acc[ri][rj][i][1] + bias[col + 1], 0.f);
        o.z = fmaxf(acc[ri][rj][i][2] + bias[col + 2], 0.f);
        o.w = fmaxf(acc[ri][rj][i][3] + bias[col + 3], 0.f);
        *(float4*)(C + (size_t)row * 1024 + col) = o;
      }
    }
}

// ---------------- K2: ner = C1 @ W2T^T + b2; softmax; argmax ----------------
__global__ __launch_bounds__(256) void k_ner(const float* __restrict__ C1,
                                             const float* __restrict__ W2T,
                                             const float* __restrict__ b2,
                                             float* __restrict__ ner_out,
                                             float* __restrict__ softm,
                                             int* __restrict__ amax) {
  const int wave = threadIdx.x >> 6, lane = threadIdx.x & 63;
  const int row0 = blockIdx.x * 16 + wave * 4;
  float acc[4][17];
#pragma unroll
  for (int r = 0; r < 4; ++r)
#pragma unroll
    for (int c = 0; c < 17; ++c) acc[r][c] = 0.f;
  for (int kb = 0; kb < 16; ++kb) {
    int k = kb * 64 + lane;
    float w2l[17];
#pragma unroll
    for (int c = 0; c < 17; ++c) w2l[c] = W2T[c * 1024 + k];
#pragma unroll
    for (int r = 0; r < 4; ++r) {
      float v = C1[(size_t)(row0 + r) * 1024 + k];
#pragma unroll
      for (int c = 0; c < 17; ++c) acc[r][c] = fmaf(v, w2l[c], acc[r][c]);
    }
  }
#pragma unroll
  for (int off = 32; off > 0; off >>= 1) {
#pragma unroll
    for (int r = 0; r < 4; ++r)
#pragma unroll
      for (int c = 0; c < 17; ++c) acc[r][c] += __shfl_xor(acc[r][c], off);
  }
  if (lane < 4) {
    const int row = row0 + lane;
    float v[17];
#pragma unroll
    for (int c = 0; c < 17; ++c) v[c] = acc[lane][c] + b2[c];
    float mx = v[0]; int am = 0;
#pragma unroll
    for (int c = 1; c < 17; ++c) { if (v[c] > mx) { mx = v[c]; am = c; } }
    float s = 0.f, e[17];
#pragma unroll
    for (int c = 0; c < 17; ++c) { e[c] = __expf(v[c] - mx); s += e[c]; }
    const float inv = 1.f / s;
    float* sm = softm + (size_t)row * 17;
#pragma unroll
    for (int c = 0; c < 17; ++c) sm[c] = e[c] * inv;
    amax[row] = am;
    const int b = row >> 10, sidx = row & 1023;
    if (sidx >= 1) {
      float* no = ner_out + ((size_t)b * SMM + sidx - 1) * 17;
#pragma unroll
      for (int c = 0; c < 17; ++c) no[c] = v[c];
    }
  }
}

// ---------------- K3: span logic (amax staged to LDS to kill serial global-latency) ----------------
__global__ __launch_bounds__(256) void k_spans(const int* __restrict__ amax,
                                               int* __restrict__ meta,
                                               float* __restrict__ pp_out) {
  const int b = blockIdx.x, tid = threadIdx.x;
  __shared__ int amS[1024];
  __shared__ int nextE[4][1023];
  __shared__ int slist[4][10], blj[4][10], ble[4][10];
  __shared__ int ns[4], nb[4];
  __shared__ int posq[10];
  // cooperative coalesced stage: all loads in flight in parallel
  for (int idx = tid; idx < 1024; idx += 256) amS[idx] = amax[b * 1024 + idx];
  __syncthreads();
  if (tid < 4) {
    const int t = tid;
    int cur = SMM;
#pragma unroll 4
    for (int j = SMM - 1; j >= 0; --j) {
      nextE[t][j] = cur;
      if (amS[j + 1] == 3 + 4 * t) cur = j;
    }
    int end = -1, cs = 0, cb = 0;
#pragma unroll 4
    for (int j = 0; j < SMM; ++j) {
      int a = amS[j + 1];
      if (a == 4 + 4 * t && cs < 10) slist[t][cs++] = j;
      if (a == 1 + 4 * t && j > end) {
        end = nextE[t][j];
        if (cb < 10) { blj[t][cb] = j; ble[t][cb] = end; cb++; }
      }
    }
    ns[t] = cs; nb[t] = cb;
  }
  __syncthreads();
  if (tid == 0) {
    int q = 0;
    for (int t = 0; t < 4 && q < 10; ++t) {
      for (int s = 0; s < ns[t] && q < 10; ++s) {
        int j = slist[t][s];
        int* m = meta + (b * 10 + q) * 4;
        m[0] = j; m[1] = j + 1; m[2] = 1; m[3] = 1;
        posq[q] = j + 1; ++q;
      }
      for (int s = 0; s < nb[t] && q < 10; ++s) {
        int j = blj[t][s], e = ble[t][s];
        int* m = meta + (b * 10 + q) * 4;
        m[0] = j; m[1] = e; m[2] = e - j; m[3] = 1;
        posq[q] = e + 1; ++q;
      }
    }
    for (; q < 10; ++q) {
      int* m = meta + (b * 10 + q) * 4;
      m[0] = 0; m[1] = 0; m[2] = 1; m[3] = 0;
      posq[q] = -1;
    }
  }
  __syncthreads();
  for (int pr = tid; pr < NPAIR; pr += 256) {
    int i = pr / 9, jj = pr % 9;
    int j = jj + (jj >= i ? 1 : 0);
    pp_out[(size_t)(b * NPAIR + pr) * 2 + 0] = (float)posq[i];
    pp_out[(size_t)(b * NPAIR + pr) * 2 + 1] = (float)posq[j];
  }
}

// ---------------- K4: ents = segment means ----------------
__global__ __launch_bounds__(256) void k_ents(const float* __restrict__ h,
                                              const float* __restrict__ softm,
                                              const int* __restrict__ meta,
                                              float* __restrict__ ents) {
  const int bq = blockIdx.x;
  const int b = bq / 10;
  const int* m = meta + bq * 4;
  const int j0 = m[0], e = m[1], len = m[2], vs = m[3];
  float acc[5] = {0.f, 0.f, 0.f, 0.f, 0.f};
  for (int row = j0; row < e; ++row) {
    const int s = row + 1;
    const float* hr = h + (size_t)(b * 1024 + s) * 1024;
    const float* sr = softm + (size_t)(b * 1024 + s) * 17;
#pragma unroll
    for (int i = 0; i < 5; ++i) {
      int d = threadIdx.x + i * 256;
      if (d < DXX) acc[i] += (d < 1024 ? hr[d] : sr[d - 1024]);
    }
  }
  const float inv = vs ? (1.0f / (float)len) : 0.0f;
#pragma unroll
  for (int i = 0; i < 5; ++i) {
    int d = threadIdx.x + i * 256;
    if (d < DXX) ents[(size_t)bq * DXX + d] = acc[i] * inv;
  }
}

// ---------------- K5a: fused head/tail layer-1 ----------------
__global__ __launch_bounds__(512) void k_mlp_l1(const float* __restrict__ ents,
                                                const float* __restrict__ Wh1, const float* __restrict__ bh1,
                                                const float* __restrict__ Wt1, const float* __restrict__ bt1,
                                                float* __restrict__ H1, float* __restrict__ T1) {
  __shared__ float e[2][DXX];
  const int r0 = blockIdx.x * 2;
  const int chain = blockIdx.y;
  const float* W = chain ? Wt1 : Wh1;
  const float* bi = chain ? bt1 : bh1;
  float* out = chain ? T1 : H1;
  for (int idx = threadIdx.x; idx < 2 * DXX; idx += 512) {
    int row = idx >= DXX;
    int col = row ? idx - DXX : idx;
    e[row][col] = ents[(size_t)(r0 + row) * DXX + col];
  }
  __syncthreads();
  const int n = threadIdx.x;
  float a0 = 0.f, a1 = 0.f;
#pragma unroll 4
  for (int k = 0; k < DXX; ++k) {
    float w = W[(size_t)k * 512 + n];
    a0 = fmaf(e[0][k], w, a0);
    a1 = fmaf(e[1][k], w, a1);
  }
  const float bv = bi[n];
  out[(size_t)r0 * 512 + n] = fmaxf(a0 + bv, 0.f);
  out[(size_t)(r0 + 1) * 512 + n] = fmaxf(a1 + bv, 0.f);
}

// ---------------- K5b: fused head/tail layer-2 ----------------
__global__ __launch_bounds__(512) void k_mlp_l2(const float* __restrict__ H1, const float* __restrict__ T1,
                                                const float* __restrict__ Wh2, const float* __restrict__ bh2,
                                                const float* __restrict__ Wt2, const float* __restrict__ bt2,
                                                float* __restrict__ headp, float* __restrict__ tailp) {
  __shared__ float e[2][512];
  const int r0 = blockIdx.x * 2;
  const int chain = blockIdx.y;
  const float* in = chain ? T1 : H1;
  const float* W = chain ? Wt2 : Wh2;
  const float* bi = chain ? bt2 : bh2;
  float* out = chain ? tailp : headp;
  for (int idx = threadIdx.x; idx < 1024; idx += 512)
    e[idx >> 9][idx & 511] = in[(size_t)r0 * 512 + idx];
  __syncthreads();
  const int n = threadIdx.x;
  float a0 = 0.f, a1 = 0.f;
#pragma unroll 4
  for (int k = 0; k < 512; ++k) {
    float w = W[(size_t)k * 512 + n];
    a0 = fmaf(e[0][k], w, a0);
    a1 = fmaf(e[1][k], w, a1);
  }
  const float bv = bi[n];
  out[(size_t)r0 * 512 + n] = a0 + bv;
  out[(size_t)(r0 + 1) * 512 + n] = a1 + bv;
}

// ---------------- K5c: bilinear u[o] = headp @ Wbil[o], 64x64 tiled reg-blocked ----------------
__global__ __launch_bounds__(256) void k_bil(const float* __restrict__ headp,
                                             const float* __restrict__ Wbil,
                                             float* __restrict__ u) {
  __shared__ float As[16][64];
  __shared__ float Bs[16][64];
  const int o = blockIdx.z;
  const int m0 = blockIdx.y * 64, n0 = blockIdx.x * 64;
  const int tx = threadIdx.x & 15, ty = threadIdx.x >> 4;
  const float* Wo = Wbil + (size_t)o * 262144;
  float acc[4][4] = {};
  for (int k0 = 0; k0 < 512; k0 += 16) {
    float4 av4 = *(const float4*)(headp + (size_t)(m0 + (threadIdx.x >> 2)) * 512 + k0 + (threadIdx.x & 3) * 4);
    float4 bv4 = *(const float4*)(Wo + (size_t)(k0 + (threadIdx.x >> 4)) * 512 + n0 + (threadIdx.x & 15) * 4);
    __syncthreads();
    As[(threadIdx.x & 3) * 4 + 0][threadIdx.x >> 2] = av4.x;
    As[(threadIdx.x & 3) * 4 + 1][threadIdx.x >> 2] = av4.y;
    As[(threadIdx.x & 3) * 4 + 2][threadIdx.x >> 2] = av4.z;
    As[(threadIdx.x & 3) * 4 + 3][threadIdx.x >> 2] = av4.w;
    *(float4*)&Bs[threadIdx.x >> 4][(threadIdx.x & 15) * 4] = bv4;
    __syncthreads();
#pragma unroll
    for (int kk = 0; kk < 16; ++kk) {
      float4 a = *(const float4*)&As[kk][ty * 4];
      float4 b = *(const float4*)&Bs[kk][tx * 4];
      float av[4] = {a.x, a.y, a.z, a.w};
      float bv[4] = {b.x, b.y, b.z, b.w};
#pragma unroll
      for (int i = 0; i < 4; ++i)
#pragma unroll
        for (int j = 0; j < 4; ++j)
          acc[i][j] = fmaf(av[i], bv[j], acc[i][j]);
    }
  }
#pragma unroll
  for (int i = 0; i < 4; ++i) {
    float4 ov = {acc[i][0], acc[i][1], acc[i][2], acc[i][3]};
    *(float4*)(u + ((size_t)o * 320 + m0 + ty * 4 + i) * 512 + n0 + tx * 4) = ov;
  }
}

// ---------------- K6: lh/lt = head/tail @ Wlin parts ----------------
__global__ __launch_bounds__(256) void k_lin(const float* __restrict__ headp,
                                             const float* __restrict__ tailp,
                                             const float* __restrict__ Wlin,
                                             float* __restrict__ lh,
                                             float* __restrict__ lt) {
  __shared__ float redH[4][16], redT[4][16];
  const int r = blockIdx.x;
  const int wv = threadIdx.x >> 6, lane = threadIdx.x & 63;
  const float* hr = headp + (size_t)r * 512;
  const float* tr = tailp + (size_t)r * 512;
  float a[16], bacc[16];
#pragma unroll
  for (int o = 0; o < 16; ++o) { a[o] = 0.f; bacc[o] = 0.f; }
#pragma unroll
  for (int kk = 0; kk < 2; ++kk) {
    const int k = wv * 128 + kk * 64 + lane;
    const float hv = hr[k], tv = tr[k];
#pragma unroll
    for (int o = 0; o < 16; ++o) {
      a[o] = fmaf(hv, Wlin[o * 1024 + k], a[o]);
      bacc[o] = fmaf(tv, Wlin[o * 1024 + 512 + k], bacc[o]);
    }
  }
#pragma unroll
  for (int off = 32; off > 0; off >>= 1) {
#pragma unroll
    for (int o = 0; o < 16; ++o) {
      a[o] += __shfl_xor(a[o], off);
      bacc[o] += __shfl_xor(bacc[o], off);
    }
  }
  if (lane == 0) {
#pragma unroll
    for (int o = 0; o < 16; ++o) { redH[wv][o] = a[o]; redT[wv][o] = bacc[o]; }
  }
  __syncthreads();
  if (threadIdx.x < 16) {
    const int o = threadIdx.x;
    float s = 0.f, t = 0.f;
#pragma unroll
    for (int w2 = 0; w2 < 4; ++w2) { s += redH[w2][o]; t += redT[w2][o]; }
    lh[r * 16 + o] = s;
    lt[r * 16 + o] = t;
  }
}

// ---------------- K7: re ----------------
__global__ __launch_bounds__(256) void k_re(const float* __restrict__ u,
                                            const float* __restrict__ tailp,
                                            const float* __restrict__ lh,
                                            const float* __restrict__ lt,
                                            const float* __restrict__ bbil,
                                            float* __restrict__ re_out) {
  const int bp = blockIdx.x;
  const int b = bp / NPAIR, pr = bp % NPAIR;
  const int i = pr / 9, jj = pr % 9;
  const int j = jj + (jj >= i ? 1 : 0);
  const int wave = threadIdx.x >> 6, lane = threadIdx.x & 63;
  const float* tj = tailp + (size_t)(b * 10 + j) * 512;
#pragma unroll
  for (int oo = 0; oo < 4; ++oo) {
    const int o = wave + oo * 4;
    const float* uo = u + ((size_t)o * 320 + b * 10 + i) * 512;
    float acc = 0.f;
    for (int k = lane; k < 512; k += 64) acc = fmaf(uo[k], tj[k], acc);
#pragma unroll
    for (int off = 32; off > 0; off >>= 1) acc += __shfl_xor(acc, off);
    if (lane == 0)
      re_out[(size_t)bp * 16 + o] = acc + bbil[o] + lh[(b * 10 + i) * 16 + o] + lt[(b * 10 + j) * 16 + o];
  }
}

// ---------------- launch ----------------
extern "C" void kernel_launch(void* const* d_in, const int* in_sizes, int n_in,
                              void* d_out, int out_size, void* d_ws, size_t ws_size,
                              hipStream_t stream) {
  const float* h    = (const float*)d_in[0];
  const float* W1   = (const float*)d_in[1];
  const float* b1   = (const float*)d_in[2];
  const float* W2   = (const float*)d_in[3];
  const float* b2   = (const float*)d_in[4];
  const float* Wh1  = (const float*)d_in[5];
  const float* bh1  = (const float*)d_in[6];
  const float* Wh2  = (const float*)d_in[7];
  const float* bh2  = (const float*)d_in[8];
  const float* Wt1  = (const float*)d_in[9];
  const float* bt1  = (const float*)d_in[10];
  const float* Wt2  = (const float*)d_in[11];
  const float* bt2  = (const float*)d_in[12];
  const float* Wbil = (const float*)d_in[13];
  const float* bbil = (const float*)d_in[14];
  const float* Wlin = (const float*)d_in[15];

  float* out = (float*)d_out;
  float* ner_out = out;
  float* pp_out  = out + 556512;
  float* re_out  = out + 562272;

  char* ws = (char*)d_ws;
  float* C1    = (float*)(ws + 0);
  float* softm = (float*)(ws + 134217728);
  int*   amax  = (int*)  (ws + 136445952);
  int*   meta  = (int*)  (ws + 136577024);
  float* ents  = (float*)(ws + 136582144);
  float* H1    = (float*)(ws + 137914624);
  float* T1    = (float*)(ws + 138569984);
  float* headp = (float*)(ws + 139225344);
  float* tailp = (float*)(ws + 139880704);
  float* u     = (float*)(ws + 140536064);
  float* lh    = (float*)(ws + 151021824);
  float* lt    = (float*)(ws + 151042304);
  float* W2T   = (float*)(ws + 151062784);
  unsigned short* wP = (unsigned short*)(ws + 151132416);
  unsigned short* hP = (unsigned short*)(ws + 157423872);
  const size_t NEED_FULL = 358750464;
  const size_t NEED_W2T  = 151132416;

  const bool full = ws_size >= NEED_FULL;
  const bool haveW2T = ws_size >= NEED_W2T;

  if (full) {
    k_split_h<<<2048, 256, 0, stream>>>((const float4*)h, (ushort4*)hP,
                                        (ushort4*)(hP + 33554432), (ushort4*)(hP + 67108864));
    k_split_w<<<dim3(32, 32), 256, 0, stream>>>(W1, wP);
    k_gemm1_8ph<<<512, 512, 0, stream>>>(hP, wP, b1, C1);
  } else {
    k_gemm1<<<dim3(8, 256), 256, 0, stream>>>(h, W1, b1, C1);
  }
  if (haveW2T) {
    k_w2t<<<dim3(17, 4), 256, 0, stream>>>(W2, W2T);
    k_ner<<<2048, 256, 0, stream>>>(C1, W2T, b2, ner_out, softm, amax);
  } else {
    k_w2t<<<dim3(17, 4), 256, 0, stream>>>(W2, (float*)(ws + 140536064));
    k_ner<<<2048, 256, 0, stream>>>(C1, (float*)(ws + 140536064), b2, ner_out, softm, amax);
  }
  k_spans<<<32, 256, 0, stream>>>(amax, meta, pp_out);
  k_ents<<<320, 256, 0, stream>>>(h, softm, meta, ents);
  k_mlp_l1<<<dim3(160, 2), 512, 0, stream>>>(ents, Wh1, bh1, Wt1, bt1, H1, T1);
  k_mlp_l2<<<dim3(160, 2), 512, 0, stream>>>(H1, T1, Wh2, bh2, Wt2, bt2, headp, tailp);
  k_bil<<<dim3(8, 5, 16), 256, 0, stream>>>(headp, Wbil, u);
  k_lin<<<320, 256, 0, stream>>>(headp, tailp, Wlin, lh, lt);
  k_re<<<2880, 256, 0, stream>>>(u, tailp, lh, lt, bbil, re_out);
}